// Round 1
// 421.646 us; speedup vs baseline: 1.1196x; 1.1196x over previous
//
#include <hip/hip_runtime.h>
#include <stdint.h>

// Problem constants
#define BATCH 4
#define NSEQ  2048
#define CDIM  1152
#define HB    16
#define DHD   72
#define D3    3456
#define NT    8192    // BATCH*NSEQ

typedef __attribute__((ext_vector_type(8))) short short8;       // 8 bf16 (4 VGPRs)
typedef __attribute__((ext_vector_type(8))) unsigned short u16x8;
typedef __attribute__((ext_vector_type(4))) unsigned short u16x4;
typedef __attribute__((ext_vector_type(4))) float f32x4;

__device__ __forceinline__ float bf2f(unsigned short u) {
  return __uint_as_float(((unsigned)u) << 16);
}
__device__ __forceinline__ unsigned short f2bf(float f) {
  unsigned u = __float_as_uint(f);
  u += 0x7FFF + ((u >> 16) & 1);   // RNE
  return (unsigned short)(u >> 16);
}

// async 16B global->LDS copy: per-lane global addr, LDS dest = wave-uniform base + lane*16
__device__ __forceinline__ void gload_lds16(const unsigned short* g, unsigned short* l) {
  __builtin_amdgcn_global_load_lds(
      (const __attribute__((address_space(1))) void*)g,
      (__attribute__((address_space(3))) void*)l, 16, 0, 0);
}

// ---------------------------------------------------------------------------
// fp32 -> bf16 conversion prepass for x, w_qkv, w_proj (memory-bound).
// ---------------------------------------------------------------------------
#define XN    ((size_t)NT * CDIM)        // 9,437,184
#define WQN   ((size_t)D3 * CDIM)        // 3,981,312
#define WPN   ((size_t)CDIM * CDIM)      // 1,327,104
#define CVT_CHUNKS ((XN + WQN + WPN) / 4)  // 3,686,400 float4 chunks

__global__ __launch_bounds__(256) void cvt_bf16(
    const float* __restrict__ x, const float* __restrict__ wq,
    const float* __restrict__ wp, unsigned short* __restrict__ xb,
    unsigned short* __restrict__ wqb, unsigned short* __restrict__ wpb) {
  size_t c = (size_t)blockIdx.x * 256 + threadIdx.x;
  if (c >= CVT_CHUNKS) return;
  const float* src;
  unsigned short* dst;
  size_t e = c * 4;
  if (e < XN) { src = x + e; dst = xb + e; }
  else if (e < XN + WQN) { src = wq + (e - XN); dst = wqb + (e - XN); }
  else { src = wp + (e - XN - WQN); dst = wpb + (e - XN - WQN); }
  f32x4 v = *(const f32x4*)src;
  u16x4 r;
#pragma unroll
  for (int i = 0; i < 4; i++) r[i] = f2bf(v[i]);
  *(u16x4*)dst = r;
}

// ---------------------------------------------------------------------------
// GEMM-BT (bf16 in): C[M,Dn] = A[M,K]*Bt[Dn,K]^T (+bias), fp32 acc.
// BM=BN=128, BK=32, 256 thr = 4 waves (2x2 of 64x64), 16x16x32 MFMA,
// global_load_lds width-16 staging (m97 structure).
// SCATTER=1: bf16 scatter: Q,K -> qkvb[s][b][h][n][72], V -> Vt[b][h][dh][n].
// SCATTER=0: fp32 out + fp32 bias.
// ---------------------------------------------------------------------------
template <int SCATTER>
__global__ __launch_bounds__(256) void gemm_bt(
    const unsigned short* __restrict__ A, const unsigned short* __restrict__ Bt,
    const float* __restrict__ bias, void* __restrict__ Cout,
    unsigned short* __restrict__ Vt, int M, int Dn, int K) {
  __shared__ __attribute__((aligned(16))) unsigned short sA[128 * 32];
  __shared__ __attribute__((aligned(16))) unsigned short sB[128 * 32];

  const int tid  = threadIdx.x;
  const int lane = tid & 63;
  const int w    = tid >> 6;
  const int wm   = w >> 1, wn = w & 1;
  const int quad = lane >> 4, l16 = lane & 15;
  const int m0 = blockIdx.y * 128, n0 = blockIdx.x * 128;

  // staging addresses: wave w copies 16-row chunks {2w,2w+1} of A and B.
  // chunk ck: lane i -> row ck*16 + i/4, col (i%4)*8  (1024 B contiguous LDS)
  const int srow = (lane >> 2);
  const int scol = (lane & 3) << 3;

  const f32x4 zero = {0.f, 0.f, 0.f, 0.f};
  f32x4 acc[4][4];
#pragma unroll
  for (int i = 0; i < 4; i++)
#pragma unroll
    for (int j = 0; j < 4; j++) acc[i][j] = zero;

  for (int kt = 0; kt < K; kt += 32) {
#pragma unroll
    for (int i = 0; i < 2; i++) {
      int ck = w * 2 + i;
      gload_lds16(A + (size_t)(m0 + ck * 16 + srow) * K + kt + scol, sA + ck * 512);
      gload_lds16(Bt + (size_t)(n0 + ck * 16 + srow) * K + kt + scol, sB + ck * 512);
    }
    __syncthreads();

    short8 a[4], b[4];
#pragma unroll
    for (int i = 0; i < 4; i++)
      a[i] = *(const short8*)(sA + (wm * 64 + i * 16 + l16) * 32 + quad * 8);
#pragma unroll
    for (int j = 0; j < 4; j++)
      b[j] = *(const short8*)(sB + (wn * 64 + j * 16 + l16) * 32 + quad * 8);

#pragma unroll
    for (int i = 0; i < 4; i++)
#pragma unroll
      for (int j = 0; j < 4; j++)
        acc[i][j] = __builtin_amdgcn_mfma_f32_16x16x32_bf16(a[i], b[j], acc[i][j], 0, 0, 0);
    __syncthreads();
  }

  // epilogue: D row = quad*4+r, col = lane&15
#pragma unroll
  for (int i = 0; i < 4; i++) {
    int row = m0 + wm * 64 + i * 16 + quad * 4;
#pragma unroll
    for (int j = 0; j < 4; j++) {
      int col = n0 + wn * 64 + j * 16 + l16;
      if (SCATTER) {
        int s  = col / CDIM;
        int rm = col - s * CDIM;
        int h  = rm / DHD;
        int dh = rm - h * DHD;
        int b_ = row >> 11;           // rows of 4 never straddle the 2048 bdry
        int n  = row & 2047;
        if (s == 2) {
#pragma unroll
          for (int r = 0; r < 4; r++)
            Vt[((size_t)(b_ * HB + h) * DHD + dh) * NSEQ + n + r] = f2bf(acc[i][j][r]);
        } else {
          unsigned short* Cb = (unsigned short*)Cout;
#pragma unroll
          for (int r = 0; r < 4; r++)
            Cb[(((size_t)(s * BATCH + b_) * HB + h) * NSEQ + (n + r)) * DHD + dh] =
                f2bf(acc[i][j][r]);
        }
      } else {
        float bb = bias ? bias[col] : 0.f;
        float* Cf = (float*)Cout;
#pragma unroll
        for (int r = 0; r < 4; r++)
          Cf[(size_t)(row + r) * Dn + col] = acc[i][j][r] + bb;
      }
    }
  }
}

// ---------------------------------------------------------------------------
// RoPE (halves convention) + RMSNorm on q,k IN-PLACE on qkvb[s][b][h][n][72].
// One block per (b,n). Trig hoisted across sel (q,k share angles); per-head
// RMS reduce parallelized 4 lanes/head x 2 waves (one per sel) + shfl.
// ---------------------------------------------------------------------------
__global__ __launch_bounds__(256) void rope_rms(
    unsigned short* __restrict__ qkvb,
    const float* __restrict__ qw, const float* __restrict__ kw) {
  const int blk = blockIdx.x;
  const int b = blk >> 11;
  const int n = blk & 2047;
  const int tid = threadIdx.x;

  __shared__ float sv[2][CDIM];
  __shared__ float srsq[2][HB];

  const float nf = (float)n;
  const float l2t_over_half = 13.287712379549449f / 36.0f;  // log2(10000)/36

  for (int e = tid; e < CDIM; e += 256) {
    int h  = e / DHD;
    int dh = e - h * DHD;
    int i  = (dh < 36) ? dh : dh - 36;
    float inv_freq = exp2f(-l2t_over_half * (float)i);
    float ang = nf * inv_freq;
    float sn, cs;
    __sincosf(ang, &sn, &cs);
#pragma unroll
    for (int sel = 0; sel < 2; sel++) {
      size_t ah = (((size_t)(sel * BATCH + b) * HB + h) * NSEQ + n) * DHD;
      float x1 = bf2f(qkvb[ah + i]);
      float x2 = bf2f(qkvb[ah + i + 36]);
      sv[sel][e] = (dh < 36) ? (x1 * cs - x2 * sn) : (x2 * cs + x1 * sn);
    }
  }
  __syncthreads();
  if (tid < 128) {   // wave0: sel=0, wave1: sel=1; 4 lanes per head
    int sel = tid >> 6;
    int h = (tid & 63) >> 2, p = tid & 3;
    float s = 0.f;
#pragma unroll
    for (int d = 0; d < 18; d++) {
      float v = sv[sel][h * DHD + p * 18 + d];
      s += v * v;
    }
    s += __shfl_xor(s, 1);
    s += __shfl_xor(s, 2);
    if (p == 0) srsq[sel][h] = rsqrtf(s * (1.0f / 72.0f) + 1e-6f);
  }
  __syncthreads();
  for (int e = tid; e < CDIM; e += 256) {
    int h  = e / DHD;
    int dh = e - h * DHD;
#pragma unroll
    for (int sel = 0; sel < 2; sel++) {
      const float* wnorm = sel ? kw : qw;
      size_t ah = (((size_t)(sel * BATCH + b) * HB + h) * NSEQ + n) * DHD;
      qkvb[ah + dh] = f2bf(sv[sel][e] * srsq[sel][h] * wnorm[dh]);
    }
  }
}

// ---------------------------------------------------------------------------
// Flash attention, no-max softmax (|S*scale| <= 72*scale by Cauchy-Schwarz
// since q,k are RMS-normed -> exp2 never overflows). Block = 128 q-rows x
// head x batch; 4 waves x (2 tiles of 16 q). KV tiles of 64.
// Staging via global_load_lds DMA: K double-buffered linear [64][72]
// (144 B rows = 9x16B -> aligned b128 frags, k=64..71 tail masked by aq[2]);
// V single-buffered linear [80][64] with both-sides XOR swizzle
// (source pre-swizzle at DMA issue + same XOR on ds_read addr; 128 B rows
// would otherwise be a 16-way read conflict). Row 72 of V = ones -> row-sum
// l via MFMA; rows 73..79 = 0. Prefetch windows: K issued post-F barrier
// (drained at E), V issued post-E (drained at next F).
// ---------------------------------------------------------------------------
#define SPW 68    // sP row stride: 136 B = 8-bank offset/row -> conflict-free writes
__global__ __launch_bounds__(256, 4) void flash_attn(
    const unsigned short* __restrict__ qkvb, const unsigned short* __restrict__ Vt,
    unsigned short* __restrict__ AO) {
  __shared__ __attribute__((aligned(16))) unsigned short sK[2 * 64 * 72];  // 18432 B
  __shared__ __attribute__((aligned(16))) unsigned short sVt[80 * 64];     // 10240 B
  __shared__ __attribute__((aligned(16))) unsigned short sP[64 * SPW];     //  8704 B

  const int tid  = threadIdx.x;
  const int w    = tid >> 6;
  const int lane = tid & 63;
  const int quad = lane >> 4, l16 = lane & 15;
  const int q0 = blockIdx.x * 128;
  const int h = blockIdx.y, b = blockIdx.z;

  const unsigned short* Qb = qkvb + ((size_t)(0 * BATCH + b) * HB + h) * NSEQ * DHD;
  const unsigned short* Kb = qkvb + ((size_t)(1 * BATCH + b) * HB + h) * NSEQ * DHD;
  const unsigned short* Vb = Vt + (size_t)(b * HB + h) * DHD * NSEQ;

  const short8 zs = {0, 0, 0, 0, 0, 0, 0, 0};
  const f32x4 zero = {0.f, 0.f, 0.f, 0.f};

  // staging source pointers; wave issue i = w + 4*j (9 x 1KB per array).
  // K tile is a straight linear copy: LDS short off = c*8 == global short off.
  // V: LDS[dh][cg] <- V[dh][cg ^ (dh&7)]  (inverse swizzle on the source).
  const int vswz = ((lane & 7) ^ (lane >> 3)) * 8;
  const unsigned short* pK[3];
  const unsigned short* pV[3];
#pragma unroll
  for (int j = 0; j < 3; j++) {
    int i = w + 4 * j;
    int ii = (i < 9) ? i : 0;
    pK[j] = Kb + ii * 512 + lane * 8;
    pV[j] = Vb + (size_t)(ii * 8 + (lane >> 3)) * NSEQ + vswz;
  }

  // issue tile-0 staging (K -> buf0, V)
#pragma unroll
  for (int j = 0; j < 3; j++) {
    int i = w + 4 * j;
    if (i < 9) {
      gload_lds16(pK[j], sK + i * 512);
      gload_lds16(pV[j], sVt + i * 512);
    }
  }

  // ones row (d=72) and zero rows (73..79) of V; staging never touches them
  for (int e = tid; e < 512; e += 256)
    sVt[72 * 64 + e] = (e < 64) ? (unsigned short)0x3F80 : (unsigned short)0;

  // Q fragments: 2 q-tiles per wave, rows q0 + w*32 + qt*16 + l16
  short8 aq[2][3];
#pragma unroll
  for (int qt = 0; qt < 2; qt++) {
    const unsigned short* qrow = Qb + (size_t)(q0 + w * 32 + qt * 16 + l16) * DHD;
    aq[qt][0] = *(const short8*)(qrow + quad * 8);
    aq[qt][1] = *(const short8*)(qrow + 32 + quad * 8);
    aq[qt][2] = (quad == 0) ? *(const short8*)(qrow + 64) : zs;
  }

  f32x4 o[2][5];
#pragma unroll
  for (int qt = 0; qt < 2; qt++)
#pragma unroll
    for (int nb = 0; nb < 5; nb++) o[qt][nb] = zero;

  const float scale2 = 0.17002329230297715f;  // 72^-0.5 * log2(e)

  __syncthreads();   // tile-0 DMA drained (compiler emits vmcnt(0) before barrier)

  auto qkt_sm = [&](int qt, const unsigned short* sKb) {
    f32x4 st[4];
    __builtin_amdgcn_s_setprio(1);
#pragma unroll
    for (int nk = 0; nk < 4; nk++) {
      const unsigned short* kr = sKb + (nk * 16 + l16) * 72;
      short8 kf0 = *(const short8*)(kr + quad * 8);
      short8 kf1 = *(const short8*)(kr + 32 + quad * 8);
      short8 kf2 = *(const short8*)(kr + 64);  // uniform; bogus k-slots masked by aq[2]=0
      f32x4 s = zero;
      s = __builtin_amdgcn_mfma_f32_16x16x32_bf16(aq[qt][0], kf0, s, 0, 0, 0);
      s = __builtin_amdgcn_mfma_f32_16x16x32_bf16(aq[qt][1], kf1, s, 0, 0, 0);
      s = __builtin_amdgcn_mfma_f32_16x16x32_bf16(aq[qt][2], kf2, s, 0, 0, 0);
      st[nk] = s;
    }
    __builtin_amdgcn_s_setprio(0);
    // P = exp2(S*scale2) -> bf16 -> per-wave LDS rows (C/D -> A layout fix)
#pragma unroll
    for (int nk = 0; nk < 4; nk++)
#pragma unroll
      for (int r = 0; r < 4; r++)
        sP[(w * 16 + quad * 4 + r) * SPW + nk * 16 + l16] =
            f2bf(exp2f(st[nk][r] * scale2));
  };

  auto pv = [&](int qt) {
    __builtin_amdgcn_s_setprio(1);
#pragma unroll
    for (int kb = 0; kb < 2; kb++) {
      short8 pf = *(const short8*)(sP + (w * 16 + l16) * SPW + kb * 32 + quad * 8);
#pragma unroll
      for (int nb = 0; nb < 5; nb++) {
        short8 vf = *(const short8*)(sVt + (nb * 16 + l16) * 64 +
                                     ((kb * 32 + quad * 8) ^ ((l16 & 7) * 8)));
        o[qt][nb] = __builtin_amdgcn_mfma_f32_16x16x32_bf16(pf, vf, o[qt][nb], 0, 0, 0);
      }
    }
    __builtin_amdgcn_s_setprio(0);
  };

  for (int t = 0; t < 32; t++) {
    const unsigned short* sKb = sK + (t & 1) * 4608;
    const int kvn = (t + 1) * 64;

    qkt_sm(0, sKb);
    __syncthreads();                 // F: V(t) DMA (issued post-E(t-1)) drained

    if (t < 31) {                    // prefetch K(t+1) -> other buffer
      unsigned short* dK = sK + ((t + 1) & 1) * 4608;
#pragma unroll
      for (int j = 0; j < 3; j++) {
        int i = w + 4 * j;
        if (i < 9) gload_lds16(pK[j] + (size_t)kvn * 72, dK + i * 512);
      }
    }

    pv(0);
    qkt_sm(1, sKb);                  // sP overwrite is wave-local, lgkm-ordered
    pv(1);
    __syncthreads();                 // E: V readers done; K(t+1) DMA drained

    if (t < 31) {                    // prefetch V(t+1); drains at next F
#pragma unroll
      for (int j = 0; j < 3; j++) {
        int i = w + 4 * j;
        if (i < 9) gload_lds16(pV[j] + kvn, sVt + i * 512);
      }
    }
  }

  // epilogue: l sits at dh=72 (nb=4, l16=8); broadcast within quad, normalize
#pragma unroll
  for (int qt = 0; qt < 2; qt++) {
    float inv[4];
#pragma unroll
    for (int r = 0; r < 4; r++)
      inv[r] = 1.0f / __shfl(o[qt][4][r], (quad << 4) + 8, 64);
    const int qrow = q0 + w * 32 + qt * 16 + quad * 4;
#pragma unroll
    for (int nb = 0; nb < 5; nb++) {
      int dh = nb * 16 + l16;
      if (dh < DHD) {
#pragma unroll
        for (int r = 0; r < 4; r++)
          AO[((size_t)b * NSEQ + qrow + r) * CDIM + h * DHD + dh] =
              f2bf(o[qt][nb][r] * inv[r]);
      }
    }
  }
}

// ---------------------------------------------------------------------------
extern "C" void kernel_launch(void* const* d_in, const int* in_sizes, int n_in,
                              void* d_out, int out_size, void* d_ws, size_t ws_size,
                              hipStream_t stream) {
  const float* x      = (const float*)d_in[0];
  const float* w_qkv  = (const float*)d_in[1];
  const float* w_proj = (const float*)d_in[2];
  const float* b_proj = (const float*)d_in[3];
  const float* qnw    = (const float*)d_in[4];
  const float* knw    = (const float*)d_in[5];
  float* out = (float*)d_out;

  char* ws = (char*)d_ws;
  // layout (bytes): xb 18.9M | wqkvb 8.0M | wprojb 2.7M | qkvb 37.7M | Vt 18.9M
  // AO aliases xb (xb dead after gemm1). Total 86.1 MB.
  unsigned short* xb    = (unsigned short*)(ws);
  unsigned short* wqkvb = (unsigned short*)(ws + 18874368);
  unsigned short* wprojb= (unsigned short*)(ws + 26836992);
  unsigned short* qkvb  = (unsigned short*)(ws + 29491200);
  unsigned short* Vt    = (unsigned short*)(ws + 67239936);
  unsigned short* AO    = xb;

  cvt_bf16<<<dim3((CVT_CHUNKS + 255) / 256), 256, 0, stream>>>(
      x, w_qkv, w_proj, xb, wqkvb, wprojb);
  gemm_bt<1><<<dim3(D3 / 128, NT / 128), 256, 0, stream>>>(
      xb, wqkvb, nullptr, qkvb, Vt, NT, D3, CDIM);
  rope_rms<<<dim3(NT), 256, 0, stream>>>(qkvb, qnw, knw);
  flash_attn<<<dim3(NSEQ / 128, HB, BATCH), 256, 0, stream>>>(qkvb, Vt, AO);
  gemm_bt<0><<<dim3(CDIM / 128, NT / 128), 256, 0, stream>>>(
      AO, wprojb, b_proj, out, nullptr, NT, CDIM, CDIM);
}

// Round 2
// 405.624 us; speedup vs baseline: 1.1638x; 1.0395x over previous
//
#include <hip/hip_runtime.h>
#include <stdint.h>

// Problem constants
#define BATCH 4
#define NSEQ  2048
#define CDIM  1152
#define HB    16
#define DHD   72
#define D3    3456
#define NT    8192    // BATCH*NSEQ

typedef __attribute__((ext_vector_type(8))) short short8;       // 8 bf16 (4 VGPRs)
typedef __attribute__((ext_vector_type(8))) unsigned short u16x8;
typedef __attribute__((ext_vector_type(4))) unsigned short u16x4;
typedef __attribute__((ext_vector_type(4))) float f32x4;

__device__ __forceinline__ float bf2f(unsigned short u) {
  return __uint_as_float(((unsigned)u) << 16);
}
__device__ __forceinline__ unsigned short f2bf(float f) {
  unsigned u = __float_as_uint(f);
  u += 0x7FFF + ((u >> 16) & 1);   // RNE
  return (unsigned short)(u >> 16);
}
// round-half-up bf16 (2 VALU ops); used for P where the tiny tie-bias
// cancels in O = (P V)/(P 1) since l uses the same packed values.
__device__ __forceinline__ unsigned short f2bf_ru(float f) {
  return (unsigned short)((__float_as_uint(f) + 0x8000u) >> 16);
}

// async 16B global->LDS copy: per-lane global addr, LDS dest = wave-uniform base + lane*16
__device__ __forceinline__ void gload_lds16(const unsigned short* g, unsigned short* l) {
  __builtin_amdgcn_global_load_lds(
      (const __attribute__((address_space(1))) void*)g,
      (__attribute__((address_space(3))) void*)l, 16, 0, 0);
}

// ---------------------------------------------------------------------------
// fp32 -> bf16 conversion prepass for x, w_qkv, w_proj (memory-bound).
// ---------------------------------------------------------------------------
#define XN    ((size_t)NT * CDIM)        // 9,437,184
#define WQN   ((size_t)D3 * CDIM)        // 3,981,312
#define WPN   ((size_t)CDIM * CDIM)      // 1,327,104
#define CVT_CHUNKS ((XN + WQN + WPN) / 4)  // 3,686,400 float4 chunks

__global__ __launch_bounds__(256) void cvt_bf16(
    const float* __restrict__ x, const float* __restrict__ wq,
    const float* __restrict__ wp, unsigned short* __restrict__ xb,
    unsigned short* __restrict__ wqb, unsigned short* __restrict__ wpb) {
  size_t c = (size_t)blockIdx.x * 256 + threadIdx.x;
  if (c >= CVT_CHUNKS) return;
  const float* src;
  unsigned short* dst;
  size_t e = c * 4;
  if (e < XN) { src = x + e; dst = xb + e; }
  else if (e < XN + WQN) { src = wq + (e - XN); dst = wqb + (e - XN); }
  else { src = wp + (e - XN - WQN); dst = wpb + (e - XN - WQN); }
  f32x4 v = *(const f32x4*)src;
  u16x4 r;
#pragma unroll
  for (int i = 0; i < 4; i++) r[i] = f2bf(v[i]);
  *(u16x4*)dst = r;
}

// ---------------------------------------------------------------------------
// GEMM-BT (bf16 in): C[M,Dn] = A[M,K]*Bt[Dn,K]^T (+bias), fp32 acc.
// BM=BN=128, BK=32, 256 thr = 4 waves (2x2 of 64x64), 16x16x32 MFMA,
// global_load_lds width-16 staging (m97 structure). XCD-bijective block
// swizzle (grids are multiples of 8).
// SCATTER=1: bf16 scatter: Q,K -> qkvb[s][b][h][n][72], V -> Vt[b][h][dh][n].
// SCATTER=0: fp32 out + fp32 bias.
// ---------------------------------------------------------------------------
template <int SCATTER>
__global__ __launch_bounds__(256) void gemm_bt(
    const unsigned short* __restrict__ A, const unsigned short* __restrict__ Bt,
    const float* __restrict__ bias, void* __restrict__ Cout,
    unsigned short* __restrict__ Vt, int M, int Dn, int K) {
  __shared__ __attribute__((aligned(16))) unsigned short sA[128 * 32];
  __shared__ __attribute__((aligned(16))) unsigned short sB[128 * 32];

  const int tid  = threadIdx.x;
  const int lane = tid & 63;
  const int w    = tid >> 6;
  const int wm   = w >> 1, wn = w & 1;
  const int quad = lane >> 4, l16 = lane & 15;

  // XCD-aware bijective swizzle: nwg % 8 == 0 for both call sites.
  const int gx  = gridDim.x;
  const int nwg = gx * gridDim.y;
  const int lb  = blockIdx.y * gx + blockIdx.x;
  const int swz = (lb & 7) * (nwg >> 3) + (lb >> 3);
  const int m0 = (swz / gx) * 128, n0 = (swz % gx) * 128;

  // staging addresses: wave w copies 16-row chunks {2w,2w+1} of A and B.
  // chunk ck: lane i -> row ck*16 + i/4, col (i%4)*8  (1024 B contiguous LDS)
  const int srow = (lane >> 2);
  const int scol = (lane & 3) << 3;

  const f32x4 zero = {0.f, 0.f, 0.f, 0.f};
  f32x4 acc[4][4];
#pragma unroll
  for (int i = 0; i < 4; i++)
#pragma unroll
    for (int j = 0; j < 4; j++) acc[i][j] = zero;

  for (int kt = 0; kt < K; kt += 32) {
#pragma unroll
    for (int i = 0; i < 2; i++) {
      int ck = w * 2 + i;
      gload_lds16(A + (size_t)(m0 + ck * 16 + srow) * K + kt + scol, sA + ck * 512);
      gload_lds16(Bt + (size_t)(n0 + ck * 16 + srow) * K + kt + scol, sB + ck * 512);
    }
    __syncthreads();

    short8 a[4], b[4];
#pragma unroll
    for (int i = 0; i < 4; i++)
      a[i] = *(const short8*)(sA + (wm * 64 + i * 16 + l16) * 32 + quad * 8);
#pragma unroll
    for (int j = 0; j < 4; j++)
      b[j] = *(const short8*)(sB + (wn * 64 + j * 16 + l16) * 32 + quad * 8);

#pragma unroll
    for (int i = 0; i < 4; i++)
#pragma unroll
      for (int j = 0; j < 4; j++)
        acc[i][j] = __builtin_amdgcn_mfma_f32_16x16x32_bf16(a[i], b[j], acc[i][j], 0, 0, 0);
    __syncthreads();
  }

  // epilogue: D row = quad*4+r, col = lane&15
#pragma unroll
  for (int i = 0; i < 4; i++) {
    int row = m0 + wm * 64 + i * 16 + quad * 4;
#pragma unroll
    for (int j = 0; j < 4; j++) {
      int col = n0 + wn * 64 + j * 16 + l16;
      if (SCATTER) {
        int s  = col / CDIM;
        int rm = col - s * CDIM;
        int h  = rm / DHD;
        int dh = rm - h * DHD;
        int b_ = row >> 11;           // rows of 4 never straddle the 2048 bdry
        int n  = row & 2047;
        if (s == 2) {
#pragma unroll
          for (int r = 0; r < 4; r++)
            Vt[((size_t)(b_ * HB + h) * DHD + dh) * NSEQ + n + r] = f2bf(acc[i][j][r]);
        } else {
          unsigned short* Cb = (unsigned short*)Cout;
#pragma unroll
          for (int r = 0; r < 4; r++)
            Cb[(((size_t)(s * BATCH + b_) * HB + h) * NSEQ + (n + r)) * DHD + dh] =
                f2bf(acc[i][j][r]);
        }
      } else {
        float bb = bias ? bias[col] : 0.f;
        float* Cf = (float*)Cout;
#pragma unroll
        for (int r = 0; r < 4; r++)
          Cf[(size_t)(row + r) * Dn + col] = acc[i][j][r] + bb;
      }
    }
  }
}

// ---------------------------------------------------------------------------
// RoPE (halves convention) + RMSNorm on q,k IN-PLACE on qkvb[s][b][h][n][72].
// One block per (b,n). Trig hoisted across sel (q,k share angles); per-head
// RMS reduce parallelized 4 lanes/head x 2 waves (one per sel) + shfl.
// Q (sel=0) is additionally pre-scaled by 72^-0.5*log2(e) so flash_attn's
// softmax is exp2(S) directly (exact fp32 multiply before bf16 rounding).
// ---------------------------------------------------------------------------
__global__ __launch_bounds__(256) void rope_rms(
    unsigned short* __restrict__ qkvb,
    const float* __restrict__ qw, const float* __restrict__ kw) {
  const int blk = blockIdx.x;
  const int b = blk >> 11;
  const int n = blk & 2047;
  const int tid = threadIdx.x;

  __shared__ float sv[2][CDIM];
  __shared__ float srsq[2][HB];

  const float nf = (float)n;
  const float l2t_over_half = 13.287712379549449f / 36.0f;  // log2(10000)/36
  const float scale2 = 0.17002329230297715f;                // 72^-0.5 * log2(e)

  for (int e = tid; e < CDIM; e += 256) {
    int h  = e / DHD;
    int dh = e - h * DHD;
    int i  = (dh < 36) ? dh : dh - 36;
    float inv_freq = exp2f(-l2t_over_half * (float)i);
    float ang = nf * inv_freq;
    float sn, cs;
    __sincosf(ang, &sn, &cs);
#pragma unroll
    for (int sel = 0; sel < 2; sel++) {
      size_t ah = (((size_t)(sel * BATCH + b) * HB + h) * NSEQ + n) * DHD;
      float x1 = bf2f(qkvb[ah + i]);
      float x2 = bf2f(qkvb[ah + i + 36]);
      sv[sel][e] = (dh < 36) ? (x1 * cs - x2 * sn) : (x2 * cs + x1 * sn);
    }
  }
  __syncthreads();
  if (tid < 128) {   // wave0: sel=0, wave1: sel=1; 4 lanes per head
    int sel = tid >> 6;
    int h = (tid & 63) >> 2, p = tid & 3;
    float s = 0.f;
#pragma unroll
    for (int d = 0; d < 18; d++) {
      float v = sv[sel][h * DHD + p * 18 + d];
      s += v * v;
    }
    s += __shfl_xor(s, 1);
    s += __shfl_xor(s, 2);
    if (p == 0)
      srsq[sel][h] = rsqrtf(s * (1.0f / 72.0f) + 1e-6f) * (sel ? 1.0f : scale2);
  }
  __syncthreads();
  for (int e = tid; e < CDIM; e += 256) {
    int h  = e / DHD;
    int dh = e - h * DHD;
#pragma unroll
    for (int sel = 0; sel < 2; sel++) {
      const float* wnorm = sel ? kw : qw;
      size_t ah = (((size_t)(sel * BATCH + b) * HB + h) * NSEQ + n) * DHD;
      qkvb[ah + dh] = f2bf(sv[sel][e] * srsq[sel][h] * wnorm[dh]);
    }
  }
}

// ---------------------------------------------------------------------------
// Flash attention, no-max softmax (Q pre-scaled; |S| <= 72*scale by
// Cauchy-Schwarz since q,k are RMS-normed -> exp2 never overflows).
// Block = 128 q-rows x head x batch; 4 waves x (2 tiles of 16 q).
// KV tiles of 64. Both q-tiles fused per phase so each K/V fragment is
// read from LDS once (not twice): S-phase fills st[2][4], PV-phase feeds
// both q-tiles per vf read. K single-buffered (S-phase completes before
// the F barrier, so K(t+1) DMA can reuse the buffer); V single-buffered
// linear [80][64] with both-sides XOR swizzle. Row 72 of V = ones ->
// row-sum l via MFMA; rows 73..79 = 0. Prefetch: K post-F (drains at E),
// V post-E (drains at next F).
// ---------------------------------------------------------------------------
#define SPW 68    // sP row stride: 136 B = 8-bank offset/row -> conflict-free writes
__global__ __launch_bounds__(256, 3) void flash_attn(
    const unsigned short* __restrict__ qkvb, const unsigned short* __restrict__ Vt,
    unsigned short* __restrict__ AO) {
  __shared__ __attribute__((aligned(16))) unsigned short sK[64 * 72];    //  9216 B
  __shared__ __attribute__((aligned(16))) unsigned short sVt[80 * 64];   // 10240 B
  __shared__ __attribute__((aligned(16))) unsigned short sP[128 * SPW];  // 17408 B

  const int tid  = threadIdx.x;
  const int w    = tid >> 6;
  const int lane = tid & 63;
  const int quad = lane >> 4, l16 = lane & 15;
  const int q0 = blockIdx.x * 128;
  const int h = blockIdx.y, b = blockIdx.z;

  const unsigned short* Qb = qkvb + ((size_t)(0 * BATCH + b) * HB + h) * NSEQ * DHD;
  const unsigned short* Kb = qkvb + ((size_t)(1 * BATCH + b) * HB + h) * NSEQ * DHD;
  const unsigned short* Vb = Vt + (size_t)(b * HB + h) * DHD * NSEQ;

  const short8 zs = {0, 0, 0, 0, 0, 0, 0, 0};
  const f32x4 zero = {0.f, 0.f, 0.f, 0.f};

  // staging source pointers; wave issue i = w + 4*j (9 x 1KB per array).
  // K tile is a straight linear copy: LDS short off = c*8 == global short off.
  // V: LDS[dh][cg] <- V[dh][cg ^ (dh&7)]  (inverse swizzle on the source).
  const int vswz = ((lane & 7) ^ (lane >> 3)) * 8;
  const unsigned short* pK[3];
  const unsigned short* pV[3];
#pragma unroll
  for (int j = 0; j < 3; j++) {
    int i = w + 4 * j;
    int ii = (i < 9) ? i : 0;
    pK[j] = Kb + ii * 512 + lane * 8;
    pV[j] = Vb + (size_t)(ii * 8 + (lane >> 3)) * NSEQ + vswz;
  }

  // issue tile-0 staging (K, V)
#pragma unroll
  for (int j = 0; j < 3; j++) {
    int i = w + 4 * j;
    if (i < 9) {
      gload_lds16(pK[j], sK + i * 512);
      gload_lds16(pV[j], sVt + i * 512);
    }
  }

  // ones row (d=72) and zero rows (73..79) of V; staging never touches them
  for (int e = tid; e < 512; e += 256)
    sVt[72 * 64 + e] = (e < 64) ? (unsigned short)0x3F80 : (unsigned short)0;

  // Q fragments: 2 q-tiles per wave, rows q0 + w*32 + qt*16 + l16
  short8 aq[2][3];
#pragma unroll
  for (int qt = 0; qt < 2; qt++) {
    const unsigned short* qrow = Qb + (size_t)(q0 + w * 32 + qt * 16 + l16) * DHD;
    aq[qt][0] = *(const short8*)(qrow + quad * 8);
    aq[qt][1] = *(const short8*)(qrow + 32 + quad * 8);
    aq[qt][2] = (quad == 0) ? *(const short8*)(qrow + 64) : zs;
  }

  f32x4 o[2][5];
#pragma unroll
  for (int qt = 0; qt < 2; qt++)
#pragma unroll
    for (int nb = 0; nb < 5; nb++) o[qt][nb] = zero;

  __syncthreads();   // tile-0 DMA drained (compiler emits vmcnt(0) before barrier)

  for (int t = 0; t < 32; t++) {
    const int kvn = (t + 1) * 64;

    // ---- S-phase: both q-tiles, each K fragment read ONCE ----
    f32x4 st[2][4];
    __builtin_amdgcn_s_setprio(1);
#pragma unroll
    for (int nk = 0; nk < 4; nk++) {
      const unsigned short* kr = sK + (nk * 16 + l16) * 72;
      short8 kf0 = *(const short8*)(kr + quad * 8);
      short8 kf1 = *(const short8*)(kr + 32 + quad * 8);
      short8 kf2 = *(const short8*)(kr + 64);  // uniform; bogus k-slots masked by aq[2]=0
      f32x4 s0 = zero, s1 = zero;
      s0 = __builtin_amdgcn_mfma_f32_16x16x32_bf16(aq[0][0], kf0, s0, 0, 0, 0);
      s1 = __builtin_amdgcn_mfma_f32_16x16x32_bf16(aq[1][0], kf0, s1, 0, 0, 0);
      s0 = __builtin_amdgcn_mfma_f32_16x16x32_bf16(aq[0][1], kf1, s0, 0, 0, 0);
      s1 = __builtin_amdgcn_mfma_f32_16x16x32_bf16(aq[1][1], kf1, s1, 0, 0, 0);
      s0 = __builtin_amdgcn_mfma_f32_16x16x32_bf16(aq[0][2], kf2, s0, 0, 0, 0);
      s1 = __builtin_amdgcn_mfma_f32_16x16x32_bf16(aq[1][2], kf2, s1, 0, 0, 0);
      st[0][nk] = s0;
      st[1][nk] = s1;
    }
    __builtin_amdgcn_s_setprio(0);

    // P = exp2(S) -> bf16 -> per-wave LDS rows (C/D -> A layout fix).
    // Rows qt*64 + w*16 + quad*4 + r: wave-local, lgkm-ordered vs the
    // pf reads below (no barrier needed for sP).
#pragma unroll
    for (int qt = 0; qt < 2; qt++)
#pragma unroll
      for (int nk = 0; nk < 4; nk++)
#pragma unroll
        for (int r = 0; r < 4; r++)
          sP[(qt * 64 + w * 16 + quad * 4 + r) * SPW + nk * 16 + l16] =
              f2bf_ru(exp2f(st[qt][nk][r]));

    __syncthreads();                 // F: all sK reads done; V(t) DMA drained

    if (t < 31) {                    // prefetch K(t+1) into the SAME buffer
#pragma unroll
      for (int j = 0; j < 3; j++) {
        int i = w + 4 * j;
        if (i < 9) gload_lds16(pK[j] + (size_t)kvn * 72, sK + i * 512);
      }
    }

    // ---- PV-phase: each V fragment read ONCE, feeds both q-tiles ----
    __builtin_amdgcn_s_setprio(1);
#pragma unroll
    for (int kb = 0; kb < 2; kb++) {
      short8 pf0 = *(const short8*)(sP + (w * 16 + l16) * SPW + kb * 32 + quad * 8);
      short8 pf1 = *(const short8*)(sP + (64 + w * 16 + l16) * SPW + kb * 32 + quad * 8);
#pragma unroll
      for (int nb = 0; nb < 5; nb++) {
        short8 vf = *(const short8*)(sVt + (nb * 16 + l16) * 64 +
                                     ((kb * 32 + quad * 8) ^ ((l16 & 7) * 8)));
        o[0][nb] = __builtin_amdgcn_mfma_f32_16x16x32_bf16(pf0, vf, o[0][nb], 0, 0, 0);
        o[1][nb] = __builtin_amdgcn_mfma_f32_16x16x32_bf16(pf1, vf, o[1][nb], 0, 0, 0);
      }
    }
    __builtin_amdgcn_s_setprio(0);
    __syncthreads();                 // E: all sVt reads done; K(t+1) DMA drained

    if (t < 31) {                    // prefetch V(t+1); drains at next F
#pragma unroll
      for (int j = 0; j < 3; j++) {
        int i = w + 4 * j;
        if (i < 9) gload_lds16(pV[j] + kvn, sVt + i * 512);
      }
    }
  }

  // epilogue: l sits at dh=72 (nb=4, l16=8); broadcast within quad, normalize
#pragma unroll
  for (int qt = 0; qt < 2; qt++) {
    float inv[4];
#pragma unroll
    for (int r = 0; r < 4; r++)
      inv[r] = 1.0f / __shfl(o[qt][4][r], (quad << 4) + 8, 64);
    const int qrow = q0 + w * 32 + qt * 16 + quad * 4;
#pragma unroll
    for (int nb = 0; nb < 5; nb++) {
      int dh = nb * 16 + l16;
      if (dh < DHD) {
#pragma unroll
        for (int r = 0; r < 4; r++)
          AO[((size_t)b * NSEQ + qrow + r) * CDIM + h * DHD + dh] =
              f2bf(o[qt][nb][r] * inv[r]);
      }
    }
  }
}

// ---------------------------------------------------------------------------
extern "C" void kernel_launch(void* const* d_in, const int* in_sizes, int n_in,
                              void* d_out, int out_size, void* d_ws, size_t ws_size,
                              hipStream_t stream) {
  const float* x      = (const float*)d_in[0];
  const float* w_qkv  = (const float*)d_in[1];
  const float* w_proj = (const float*)d_in[2];
  const float* b_proj = (const float*)d_in[3];
  const float* qnw    = (const float*)d_in[4];
  const float* knw    = (const float*)d_in[5];
  float* out = (float*)d_out;

  char* ws = (char*)d_ws;
  // layout (bytes): xb 18.9M | wqkvb 8.0M | wprojb 2.7M | qkvb 37.7M | Vt 18.9M
  // AO aliases xb (xb dead after gemm1). Total 86.1 MB.
  unsigned short* xb    = (unsigned short*)(ws);
  unsigned short* wqkvb = (unsigned short*)(ws + 18874368);
  unsigned short* wprojb= (unsigned short*)(ws + 26836992);
  unsigned short* qkvb  = (unsigned short*)(ws + 29491200);
  unsigned short* Vt    = (unsigned short*)(ws + 67239936);
  unsigned short* AO    = xb;

  cvt_bf16<<<dim3((CVT_CHUNKS + 255) / 256), 256, 0, stream>>>(
      x, w_qkv, w_proj, xb, wqkvb, wprojb);
  gemm_bt<1><<<dim3(D3 / 128, NT / 128), 256, 0, stream>>>(
      xb, wqkvb, nullptr, qkvb, Vt, NT, D3, CDIM);
  rope_rms<<<dim3(NT), 256, 0, stream>>>(qkvb, qnw, knw);
  flash_attn<<<dim3(NSEQ / 128, HB, BATCH), 256, 0, stream>>>(qkvb, Vt, AO);
  gemm_bt<0><<<dim3(CDIM / 128, NT / 128), 256, 0, stream>>>(
      AO, wprojb, b_proj, out, nullptr, NT, CDIM, CDIM);
}

// Round 3
// 402.079 us; speedup vs baseline: 1.1740x; 1.0088x over previous
//
#include <hip/hip_runtime.h>
#include <stdint.h>

// Problem constants
#define BATCH 4
#define NSEQ  2048
#define CDIM  1152
#define HB    16
#define DHD   72
#define D3    3456
#define NT    8192    // BATCH*NSEQ

typedef __attribute__((ext_vector_type(8))) short short8;       // 8 bf16 (4 VGPRs)
typedef __attribute__((ext_vector_type(8))) unsigned short u16x8;
typedef __attribute__((ext_vector_type(4))) unsigned short u16x4;
typedef __attribute__((ext_vector_type(4))) float f32x4;

__device__ __forceinline__ float bf2f(unsigned short u) {
  return __uint_as_float(((unsigned)u) << 16);
}
__device__ __forceinline__ unsigned short f2bf(float f) {
  unsigned u = __float_as_uint(f);
  u += 0x7FFF + ((u >> 16) & 1);   // RNE
  return (unsigned short)(u >> 16);
}
// round-half-up bf16 (2 VALU ops); used for P where the tiny tie-bias
// cancels in O = (P V)/(P 1) since l uses the same packed values.
__device__ __forceinline__ unsigned short f2bf_ru(float f) {
  return (unsigned short)((__float_as_uint(f) + 0x8000u) >> 16);
}

// async 16B global->LDS copy: per-lane global addr, LDS dest = wave-uniform base + lane*16
__device__ __forceinline__ void gload_lds16(const unsigned short* g, unsigned short* l) {
  __builtin_amdgcn_global_load_lds(
      (const __attribute__((address_space(1))) void*)g,
      (__attribute__((address_space(3))) void*)l, 16, 0, 0);
}

// ---------------------------------------------------------------------------
// fp32 -> bf16 conversion prepass for x, w_qkv, w_proj (memory-bound).
// ---------------------------------------------------------------------------
#define XN    ((size_t)NT * CDIM)        // 9,437,184
#define WQN   ((size_t)D3 * CDIM)        // 3,981,312
#define WPN   ((size_t)CDIM * CDIM)      // 1,327,104
#define CVT_CHUNKS ((XN + WQN + WPN) / 4)  // 3,686,400 float4 chunks

__global__ __launch_bounds__(256) void cvt_bf16(
    const float* __restrict__ x, const float* __restrict__ wq,
    const float* __restrict__ wp, unsigned short* __restrict__ xb,
    unsigned short* __restrict__ wqb, unsigned short* __restrict__ wpb) {
  size_t c = (size_t)blockIdx.x * 256 + threadIdx.x;
  if (c >= CVT_CHUNKS) return;
  const float* src;
  unsigned short* dst;
  size_t e = c * 4;
  if (e < XN) { src = x + e; dst = xb + e; }
  else if (e < XN + WQN) { src = wq + (e - XN); dst = wqb + (e - XN); }
  else { src = wp + (e - XN - WQN); dst = wpb + (e - XN - WQN); }
  f32x4 v = *(const f32x4*)src;
  u16x4 r;
#pragma unroll
  for (int i = 0; i < 4; i++) r[i] = f2bf(v[i]);
  *(u16x4*)dst = r;
}

// ---------------------------------------------------------------------------
// GEMM-BT (bf16 in): C[M,Dn] = A[M,K]*Bt[Dn,K]^T (+bias), fp32 acc.
// BM=BN=128, BK=32, 256 thr = 4 waves (2x2 of 64x64), 16x16x32 MFMA,
// global_load_lds width-16 staging (m97 structure). XCD-bijective block
// swizzle (grids are multiples of 8).
// SCATTER=1: bf16 scatter: Q,K -> qkvb[s][b][h][n][72], V -> Vt[b][h][dh][n].
// SCATTER=0: fp32 out + fp32 bias.
// ---------------------------------------------------------------------------
template <int SCATTER>
__global__ __launch_bounds__(256) void gemm_bt(
    const unsigned short* __restrict__ A, const unsigned short* __restrict__ Bt,
    const float* __restrict__ bias, void* __restrict__ Cout,
    unsigned short* __restrict__ Vt, int M, int Dn, int K) {
  __shared__ __attribute__((aligned(16))) unsigned short sA[128 * 32];
  __shared__ __attribute__((aligned(16))) unsigned short sB[128 * 32];

  const int tid  = threadIdx.x;
  const int lane = tid & 63;
  const int w    = tid >> 6;
  const int wm   = w >> 1, wn = w & 1;
  const int quad = lane >> 4, l16 = lane & 15;

  // XCD-aware bijective swizzle: nwg % 8 == 0 for both call sites.
  const int gx  = gridDim.x;
  const int nwg = gx * gridDim.y;
  const int lb  = blockIdx.y * gx + blockIdx.x;
  const int swz = (lb & 7) * (nwg >> 3) + (lb >> 3);
  const int m0 = (swz / gx) * 128, n0 = (swz % gx) * 128;

  // staging addresses: wave w copies 16-row chunks {2w,2w+1} of A and B.
  // chunk ck: lane i -> row ck*16 + i/4, col (i%4)*8  (1024 B contiguous LDS)
  const int srow = (lane >> 2);
  const int scol = (lane & 3) << 3;

  const f32x4 zero = {0.f, 0.f, 0.f, 0.f};
  f32x4 acc[4][4];
#pragma unroll
  for (int i = 0; i < 4; i++)
#pragma unroll
    for (int j = 0; j < 4; j++) acc[i][j] = zero;

  for (int kt = 0; kt < K; kt += 32) {
#pragma unroll
    for (int i = 0; i < 2; i++) {
      int ck = w * 2 + i;
      gload_lds16(A + (size_t)(m0 + ck * 16 + srow) * K + kt + scol, sA + ck * 512);
      gload_lds16(Bt + (size_t)(n0 + ck * 16 + srow) * K + kt + scol, sB + ck * 512);
    }
    __syncthreads();

    short8 a[4], b[4];
#pragma unroll
    for (int i = 0; i < 4; i++)
      a[i] = *(const short8*)(sA + (wm * 64 + i * 16 + l16) * 32 + quad * 8);
#pragma unroll
    for (int j = 0; j < 4; j++)
      b[j] = *(const short8*)(sB + (wn * 64 + j * 16 + l16) * 32 + quad * 8);

#pragma unroll
    for (int i = 0; i < 4; i++)
#pragma unroll
      for (int j = 0; j < 4; j++)
        acc[i][j] = __builtin_amdgcn_mfma_f32_16x16x32_bf16(a[i], b[j], acc[i][j], 0, 0, 0);
    __syncthreads();
  }

  // epilogue: D row = quad*4+r, col = lane&15
#pragma unroll
  for (int i = 0; i < 4; i++) {
    int row = m0 + wm * 64 + i * 16 + quad * 4;
#pragma unroll
    for (int j = 0; j < 4; j++) {
      int col = n0 + wn * 64 + j * 16 + l16;
      if (SCATTER) {
        int s  = col / CDIM;
        int rm = col - s * CDIM;
        int h  = rm / DHD;
        int dh = rm - h * DHD;
        int b_ = row >> 11;           // rows of 4 never straddle the 2048 bdry
        int n  = row & 2047;
        if (s == 2) {
#pragma unroll
          for (int r = 0; r < 4; r++)
            Vt[((size_t)(b_ * HB + h) * DHD + dh) * NSEQ + n + r] = f2bf(acc[i][j][r]);
        } else {
          unsigned short* Cb = (unsigned short*)Cout;
#pragma unroll
          for (int r = 0; r < 4; r++)
            Cb[(((size_t)(s * BATCH + b_) * HB + h) * NSEQ + (n + r)) * DHD + dh] =
                f2bf(acc[i][j][r]);
        }
      } else {
        float bb = bias ? bias[col] : 0.f;
        float* Cf = (float*)Cout;
#pragma unroll
        for (int r = 0; r < 4; r++)
          Cf[(size_t)(row + r) * Dn + col] = acc[i][j][r] + bb;
      }
    }
  }
}

// ---------------------------------------------------------------------------
// RoPE (halves convention) + RMSNorm on q,k IN-PLACE on qkvb[s][b][h][n][72].
// One block per (b,n). Trig hoisted across sel (q,k share angles); per-head
// RMS reduce parallelized 4 lanes/head x 2 waves (one per sel) + shfl.
// Q (sel=0) is additionally pre-scaled by 72^-0.5*log2(e) so flash_attn's
// softmax is exp2(S) directly (exact fp32 multiply before bf16 rounding).
// ---------------------------------------------------------------------------
__global__ __launch_bounds__(256) void rope_rms(
    unsigned short* __restrict__ qkvb,
    const float* __restrict__ qw, const float* __restrict__ kw) {
  const int blk = blockIdx.x;
  const int b = blk >> 11;
  const int n = blk & 2047;
  const int tid = threadIdx.x;

  __shared__ float sv[2][CDIM];
  __shared__ float srsq[2][HB];

  const float nf = (float)n;
  const float l2t_over_half = 13.287712379549449f / 36.0f;  // log2(10000)/36
  const float scale2 = 0.17002329230297715f;                // 72^-0.5 * log2(e)

  for (int e = tid; e < CDIM; e += 256) {
    int h  = e / DHD;
    int dh = e - h * DHD;
    int i  = (dh < 36) ? dh : dh - 36;
    float inv_freq = exp2f(-l2t_over_half * (float)i);
    float ang = nf * inv_freq;
    float sn, cs;
    __sincosf(ang, &sn, &cs);
#pragma unroll
    for (int sel = 0; sel < 2; sel++) {
      size_t ah = (((size_t)(sel * BATCH + b) * HB + h) * NSEQ + n) * DHD;
      float x1 = bf2f(qkvb[ah + i]);
      float x2 = bf2f(qkvb[ah + i + 36]);
      sv[sel][e] = (dh < 36) ? (x1 * cs - x2 * sn) : (x2 * cs + x1 * sn);
    }
  }
  __syncthreads();
  if (tid < 128) {   // wave0: sel=0, wave1: sel=1; 4 lanes per head
    int sel = tid >> 6;
    int h = (tid & 63) >> 2, p = tid & 3;
    float s = 0.f;
#pragma unroll
    for (int d = 0; d < 18; d++) {
      float v = sv[sel][h * DHD + p * 18 + d];
      s += v * v;
    }
    s += __shfl_xor(s, 1);
    s += __shfl_xor(s, 2);
    if (p == 0)
      srsq[sel][h] = rsqrtf(s * (1.0f / 72.0f) + 1e-6f) * (sel ? 1.0f : scale2);
  }
  __syncthreads();
  for (int e = tid; e < CDIM; e += 256) {
    int h  = e / DHD;
    int dh = e - h * DHD;
#pragma unroll
    for (int sel = 0; sel < 2; sel++) {
      const float* wnorm = sel ? kw : qw;
      size_t ah = (((size_t)(sel * BATCH + b) * HB + h) * NSEQ + n) * DHD;
      qkvb[ah + dh] = f2bf(sv[sel][e] * srsq[sel][h] * wnorm[dh]);
    }
  }
}

// ---------------------------------------------------------------------------
// Flash attention, no-max softmax (Q pre-scaled; exp2 never overflows since
// q,k are RMS-normed). Block = 128 q-rows x head x batch; 4 waves x
// (2 fused q-tiles of 16). KV tiles of 64.
// Pipelined schedule (per tile t, 2 barriers):
//   [pf(t) reads; PV(t) MFMAs]                 <- V(t),P(t) ready at entry
//   M: barrier (V readers done)
//   issue V(t+1) DMA -> sVt ; issue K(t+2) DMA -> sK[t&1]
//   [S(t+1) MFMAs from sK[(t+1)&1]; exp2+pack(t+1) -> sP]  <- hides DMA
//   A: barrier (vmcnt(0) drains V(t+1), K(t+2))
// K double-buffered (issued 1.5 tiles ahead); V single-buffered linear
// [80][64] with both-sides XOR swizzle. Row 72 of V = ones -> row-sum l via
// MFMA; rows 73..79 = 0. sP single-buffered: pf(t) reads precede the M
// barrier; pack(t+1) writes only the wave's own rows after it.
// ---------------------------------------------------------------------------
#define SPW 68    // sP row stride: 136 B = 8-bank offset/row -> conflict-free writes
__global__ __launch_bounds__(256, 3) void flash_attn(
    const unsigned short* __restrict__ qkvb, const unsigned short* __restrict__ Vt,
    unsigned short* __restrict__ AO) {
  __shared__ __attribute__((aligned(16))) unsigned short sK[2 * 64 * 72];  // 18432 B
  __shared__ __attribute__((aligned(16))) unsigned short sVt[80 * 64];     // 10240 B
  __shared__ __attribute__((aligned(16))) unsigned short sP[128 * SPW];    // 17408 B

  const int tid  = threadIdx.x;
  const int w    = tid >> 6;
  const int lane = tid & 63;
  const int quad = lane >> 4, l16 = lane & 15;
  const int q0 = blockIdx.x * 128;
  const int h = blockIdx.y, b = blockIdx.z;

  const unsigned short* Qb = qkvb + ((size_t)(0 * BATCH + b) * HB + h) * NSEQ * DHD;
  const unsigned short* Kb = qkvb + ((size_t)(1 * BATCH + b) * HB + h) * NSEQ * DHD;
  const unsigned short* Vb = Vt + (size_t)(b * HB + h) * DHD * NSEQ;

  const short8 zs = {0, 0, 0, 0, 0, 0, 0, 0};
  const f32x4 zero = {0.f, 0.f, 0.f, 0.f};

  // staging source pointers; wave issue i = w + 4*j (9 x 1KB per array).
  // K tile is a straight linear copy: LDS short off = c*8 == global short off.
  // V: LDS[dh][cg] <- V[dh][cg ^ (dh&7)]  (inverse swizzle on the source).
  const int vswz = ((lane & 7) ^ (lane >> 3)) * 8;
  const int iw = w;  // wave's issue index base
  const unsigned short* pKn[3];  // next K tile to ISSUE (rolls by 64*72)
  const unsigned short* pVn[3];  // next V tile to ISSUE (rolls by 64)
#pragma unroll
  for (int j = 0; j < 3; j++) {
    int i = iw + 4 * j;
    int ii = (i < 9) ? i : 0;
    pKn[j] = Kb + ii * 512 + lane * 8;
    pVn[j] = Vb + (size_t)(ii * 8 + (lane >> 3)) * NSEQ + vswz;
  }

  // prologue: issue K(0) -> sK[0] and V(0) -> sVt
#pragma unroll
  for (int j = 0; j < 3; j++) {
    int i = iw + 4 * j;
    if (i < 9) {
      gload_lds16(pKn[j], sK + i * 512);
      gload_lds16(pVn[j], sVt + i * 512);
    }
  }

  // ones row (d=72) and zero rows (73..79) of V; staging never touches them
  for (int e = tid; e < 512; e += 256)
    sVt[72 * 64 + e] = (e < 64) ? (unsigned short)0x3F80 : (unsigned short)0;

  // Q fragments: 2 q-tiles per wave, rows q0 + w*32 + qt*16 + l16
  short8 aq[2][3];
#pragma unroll
  for (int qt = 0; qt < 2; qt++) {
    const unsigned short* qrow = Qb + (size_t)(q0 + w * 32 + qt * 16 + l16) * DHD;
    aq[qt][0] = *(const short8*)(qrow + quad * 8);
    aq[qt][1] = *(const short8*)(qrow + 32 + quad * 8);
    aq[qt][2] = (quad == 0) ? *(const short8*)(qrow + 64) : zs;
  }

  f32x4 o[2][5];
#pragma unroll
  for (int qt = 0; qt < 2; qt++)
#pragma unroll
    for (int nb = 0; nb < 5; nb++) o[qt][nb] = zero;

  // S-phase + pack for one KV tile from the given sK buffer (both q-tiles;
  // each K fragment read once). Writes the wave's own sP rows.
  auto sphase_pack = [&](const unsigned short* sKb) {
    f32x4 st[2][4];
    __builtin_amdgcn_s_setprio(1);
#pragma unroll
    for (int nk = 0; nk < 4; nk++) {
      const unsigned short* kr = sKb + (nk * 16 + l16) * 72;
      short8 kf0 = *(const short8*)(kr + quad * 8);
      short8 kf1 = *(const short8*)(kr + 32 + quad * 8);
      short8 kf2 = *(const short8*)(kr + 64);  // uniform; bogus k-slots masked by aq[2]=0
      f32x4 s0 = zero, s1 = zero;
      s0 = __builtin_amdgcn_mfma_f32_16x16x32_bf16(aq[0][0], kf0, s0, 0, 0, 0);
      s1 = __builtin_amdgcn_mfma_f32_16x16x32_bf16(aq[1][0], kf0, s1, 0, 0, 0);
      s0 = __builtin_amdgcn_mfma_f32_16x16x32_bf16(aq[0][1], kf1, s0, 0, 0, 0);
      s1 = __builtin_amdgcn_mfma_f32_16x16x32_bf16(aq[1][1], kf1, s1, 0, 0, 0);
      s0 = __builtin_amdgcn_mfma_f32_16x16x32_bf16(aq[0][2], kf2, s0, 0, 0, 0);
      s1 = __builtin_amdgcn_mfma_f32_16x16x32_bf16(aq[1][2], kf2, s1, 0, 0, 0);
      st[0][nk] = s0;
      st[1][nk] = s1;
    }
    __builtin_amdgcn_s_setprio(0);
#pragma unroll
    for (int qt = 0; qt < 2; qt++)
#pragma unroll
      for (int nk = 0; nk < 4; nk++)
#pragma unroll
        for (int r = 0; r < 4; r++)
          sP[(qt * 64 + w * 16 + quad * 4 + r) * SPW + nk * 16 + l16] =
              f2bf_ru(exp2f(st[qt][nk][r]));
  };

  // PV for the current tile: each V fragment read once, feeds both q-tiles.
  auto pv_phase = [&]() {
    __builtin_amdgcn_s_setprio(1);
#pragma unroll
    for (int kb = 0; kb < 2; kb++) {
      short8 pf0 = *(const short8*)(sP + (w * 16 + l16) * SPW + kb * 32 + quad * 8);
      short8 pf1 = *(const short8*)(sP + (64 + w * 16 + l16) * SPW + kb * 32 + quad * 8);
#pragma unroll
      for (int nb = 0; nb < 5; nb++) {
        short8 vf = *(const short8*)(sVt + (nb * 16 + l16) * 64 +
                                     ((kb * 32 + quad * 8) ^ ((l16 & 7) * 8)));
        o[0][nb] = __builtin_amdgcn_mfma_f32_16x16x32_bf16(pf0, vf, o[0][nb], 0, 0, 0);
        o[1][nb] = __builtin_amdgcn_mfma_f32_16x16x32_bf16(pf1, vf, o[1][nb], 0, 0, 0);
      }
    }
    __builtin_amdgcn_s_setprio(0);
  };

  __syncthreads();   // drain K(0), V(0)

  // issue K(1) -> sK[1]
#pragma unroll
  for (int j = 0; j < 3; j++) {
    int i = iw + 4 * j;
    if (i < 9) gload_lds16(pKn[j] + 64 * 72, sK + 4608 + i * 512);
    pKn[j] += 2 * 64 * 72;   // next K issue = K(2)
  }

  sphase_pack(sK);           // S(0) + pack(0) from sK[0]
  __syncthreads();           // drain K(1)

  for (int t = 0; t < 32; t++) {
    pv_phase();              // PV(t): reads sVt=V(t), sP=P(t)

    if (t < 31) {
      __syncthreads();       // M: all V(t)/P(t) reads done

      // issue V(t+1) -> sVt
#pragma unroll
      for (int j = 0; j < 3; j++) {
        int i = iw + 4 * j;
        if (i < 9) gload_lds16(pVn[j] + 64, sVt + i * 512);
        pVn[j] += 64;
      }
      // issue K(t+2) -> sK[t&1] (its last reader S(t) finished last tile)
      if (t < 30) {
#pragma unroll
        for (int j = 0; j < 3; j++) {
          int i = iw + 4 * j;
          if (i < 9) gload_lds16(pKn[j], sK + (t & 1) * 4608 + i * 512);
          pKn[j] += 64 * 72;
        }
      }

      sphase_pack(sK + ((t + 1) & 1) * 4608);  // S(t+1) + pack(t+1), hides DMA
      __syncthreads();       // A: vmcnt(0) drains V(t+1), K(t+2)
    }
  }

  // epilogue: l sits at dh=72 (nb=4, l16=8); broadcast within quad, normalize
#pragma unroll
  for (int qt = 0; qt < 2; qt++) {
    float inv[4];
#pragma unroll
    for (int r = 0; r < 4; r++)
      inv[r] = 1.0f / __shfl(o[qt][4][r], (quad << 4) + 8, 64);
    const int qrow = q0 + w * 32 + qt * 16 + quad * 4;
#pragma unroll
    for (int nb = 0; nb < 5; nb++) {
      int dh = nb * 16 + l16;
      if (dh < DHD) {
#pragma unroll
        for (int r = 0; r < 4; r++)
          AO[((size_t)b * NSEQ + qrow + r) * CDIM + h * DHD + dh] =
              f2bf(o[qt][nb][r] * inv[r]);
      }
    }
  }
}

// ---------------------------------------------------------------------------
extern "C" void kernel_launch(void* const* d_in, const int* in_sizes, int n_in,
                              void* d_out, int out_size, void* d_ws, size_t ws_size,
                              hipStream_t stream) {
  const float* x      = (const float*)d_in[0];
  const float* w_qkv  = (const float*)d_in[1];
  const float* w_proj = (const float*)d_in[2];
  const float* b_proj = (const float*)d_in[3];
  const float* qnw    = (const float*)d_in[4];
  const float* knw    = (const float*)d_in[5];
  float* out = (float*)d_out;

  char* ws = (char*)d_ws;
  // layout (bytes): xb 18.9M | wqkvb 8.0M | wprojb 2.7M | qkvb 37.7M | Vt 18.9M
  // AO aliases xb (xb dead after gemm1). Total 86.1 MB.
  unsigned short* xb    = (unsigned short*)(ws);
  unsigned short* wqkvb = (unsigned short*)(ws + 18874368);
  unsigned short* wprojb= (unsigned short*)(ws + 26836992);
  unsigned short* qkvb  = (unsigned short*)(ws + 29491200);
  unsigned short* Vt    = (unsigned short*)(ws + 67239936);
  unsigned short* AO    = xb;

  cvt_bf16<<<dim3((CVT_CHUNKS + 255) / 256), 256, 0, stream>>>(
      x, w_qkv, w_proj, xb, wqkvb, wprojb);
  gemm_bt<1><<<dim3(D3 / 128, NT / 128), 256, 0, stream>>>(
      xb, wqkvb, nullptr, qkvb, Vt, NT, D3, CDIM);
  rope_rms<<<dim3(NT), 256, 0, stream>>>(qkvb, qnw, knw);
  flash_attn<<<dim3(NSEQ / 128, HB, BATCH), 256, 0, stream>>>(qkvb, Vt, AO);
  gemm_bt<0><<<dim3(CDIM / 128, NT / 128), 256, 0, stream>>>(
      AO, wprojb, b_proj, out, nullptr, NT, CDIM, CDIM);
}

// Round 4
// 395.763 us; speedup vs baseline: 1.1928x; 1.0160x over previous
//
#include <hip/hip_runtime.h>
#include <stdint.h>

// Problem constants
#define BATCH 4
#define NSEQ  2048
#define CDIM  1152
#define HB    16
#define DHD   72
#define D3    3456
#define NT    8192    // BATCH*NSEQ

typedef __attribute__((ext_vector_type(8))) short short8;       // 8 bf16 (4 VGPRs)
typedef __attribute__((ext_vector_type(8))) unsigned short u16x8;
typedef __attribute__((ext_vector_type(4))) unsigned short u16x4;
typedef __attribute__((ext_vector_type(4))) float f32x4;

__device__ __forceinline__ float bf2f(unsigned short u) {
  return __uint_as_float(((unsigned)u) << 16);
}
__device__ __forceinline__ unsigned short f2bf(float f) {
  unsigned u = __float_as_uint(f);
  u += 0x7FFF + ((u >> 16) & 1);   // RNE
  return (unsigned short)(u >> 16);
}
// round-half-up bf16 (2 VALU ops); used for P where the tiny tie-bias
// cancels in O = (P V)/(P 1) since l uses the same packed values.
__device__ __forceinline__ unsigned short f2bf_ru(float f) {
  return (unsigned short)((__float_as_uint(f) + 0x8000u) >> 16);
}

// async 16B global->LDS copy: per-lane global addr, LDS dest = wave-uniform base + lane*16
__device__ __forceinline__ void gload_lds16(const unsigned short* g, unsigned short* l) {
  __builtin_amdgcn_global_load_lds(
      (const __attribute__((address_space(1))) void*)g,
      (__attribute__((address_space(3))) void*)l, 16, 0, 0);
}

// ---------------------------------------------------------------------------
// fp32 -> bf16 conversion prepass for x, w_qkv, w_proj (memory-bound).
// ---------------------------------------------------------------------------
#define XN    ((size_t)NT * CDIM)        // 9,437,184
#define WQN   ((size_t)D3 * CDIM)        // 3,981,312
#define WPN   ((size_t)CDIM * CDIM)      // 1,327,104
#define CVT_CHUNKS ((XN + WQN + WPN) / 4)  // 3,686,400 float4 chunks

__global__ __launch_bounds__(256) void cvt_bf16(
    const float* __restrict__ x, const float* __restrict__ wq,
    const float* __restrict__ wp, unsigned short* __restrict__ xb,
    unsigned short* __restrict__ wqb, unsigned short* __restrict__ wpb) {
  size_t c = (size_t)blockIdx.x * 256 + threadIdx.x;
  if (c >= CVT_CHUNKS) return;
  const float* src;
  unsigned short* dst;
  size_t e = c * 4;
  if (e < XN) { src = x + e; dst = xb + e; }
  else if (e < XN + WQN) { src = wq + (e - XN); dst = wqb + (e - XN); }
  else { src = wp + (e - XN - WQN); dst = wpb + (e - XN - WQN); }
  f32x4 v = *(const f32x4*)src;
  u16x4 r;
#pragma unroll
  for (int i = 0; i < 4; i++) r[i] = f2bf(v[i]);
  *(u16x4*)dst = r;
}

// ---------------------------------------------------------------------------
// GEMM-BT (bf16 in): C[M,Dn] = A[M,K]*Bt[Dn,K]^T (+bias), fp32 acc.
// BM=BN=128, BK=32, 256 thr = 4 waves (2x2 of 64x64), 16x16x32 MFMA,
// global_load_lds width-16 staging (m97 structure). XCD-bijective block
// swizzle (grids are multiples of 8).
// SCATTER=1: bf16 scatter: Q,K -> qkvb[s][b][h][n][72], V -> Vt[b][h][dh][n].
// SCATTER=0: fp32 out + fp32 bias.
// ---------------------------------------------------------------------------
template <int SCATTER>
__global__ __launch_bounds__(256) void gemm_bt(
    const unsigned short* __restrict__ A, const unsigned short* __restrict__ Bt,
    const float* __restrict__ bias, void* __restrict__ Cout,
    unsigned short* __restrict__ Vt, int M, int Dn, int K) {
  __shared__ __attribute__((aligned(16))) unsigned short sA[128 * 32];
  __shared__ __attribute__((aligned(16))) unsigned short sB[128 * 32];

  const int tid  = threadIdx.x;
  const int lane = tid & 63;
  const int w    = tid >> 6;
  const int wm   = w >> 1, wn = w & 1;
  const int quad = lane >> 4, l16 = lane & 15;

  // XCD-aware bijective swizzle: nwg % 8 == 0 for both call sites.
  const int gx  = gridDim.x;
  const int nwg = gx * gridDim.y;
  const int lb  = blockIdx.y * gx + blockIdx.x;
  const int swz = (lb & 7) * (nwg >> 3) + (lb >> 3);
  const int m0 = (swz / gx) * 128, n0 = (swz % gx) * 128;

  // staging addresses: wave w copies 16-row chunks {2w,2w+1} of A and B.
  // chunk ck: lane i -> row ck*16 + i/4, col (i%4)*8  (1024 B contiguous LDS)
  const int srow = (lane >> 2);
  const int scol = (lane & 3) << 3;

  const f32x4 zero = {0.f, 0.f, 0.f, 0.f};
  f32x4 acc[4][4];
#pragma unroll
  for (int i = 0; i < 4; i++)
#pragma unroll
    for (int j = 0; j < 4; j++) acc[i][j] = zero;

  for (int kt = 0; kt < K; kt += 32) {
#pragma unroll
    for (int i = 0; i < 2; i++) {
      int ck = w * 2 + i;
      gload_lds16(A + (size_t)(m0 + ck * 16 + srow) * K + kt + scol, sA + ck * 512);
      gload_lds16(Bt + (size_t)(n0 + ck * 16 + srow) * K + kt + scol, sB + ck * 512);
    }
    __syncthreads();

    short8 a[4], b[4];
#pragma unroll
    for (int i = 0; i < 4; i++)
      a[i] = *(const short8*)(sA + (wm * 64 + i * 16 + l16) * 32 + quad * 8);
#pragma unroll
    for (int j = 0; j < 4; j++)
      b[j] = *(const short8*)(sB + (wn * 64 + j * 16 + l16) * 32 + quad * 8);

#pragma unroll
    for (int i = 0; i < 4; i++)
#pragma unroll
      for (int j = 0; j < 4; j++)
        acc[i][j] = __builtin_amdgcn_mfma_f32_16x16x32_bf16(a[i], b[j], acc[i][j], 0, 0, 0);
    __syncthreads();
  }

  // epilogue: D row = quad*4+r, col = lane&15
#pragma unroll
  for (int i = 0; i < 4; i++) {
    int row = m0 + wm * 64 + i * 16 + quad * 4;
#pragma unroll
    for (int j = 0; j < 4; j++) {
      int col = n0 + wn * 64 + j * 16 + l16;
      if (SCATTER) {
        int s  = col / CDIM;
        int rm = col - s * CDIM;
        int h  = rm / DHD;
        int dh = rm - h * DHD;
        int b_ = row >> 11;           // rows of 4 never straddle the 2048 bdry
        int n  = row & 2047;
        if (s == 2) {
#pragma unroll
          for (int r = 0; r < 4; r++)
            Vt[((size_t)(b_ * HB + h) * DHD + dh) * NSEQ + n + r] = f2bf(acc[i][j][r]);
        } else {
          unsigned short* Cb = (unsigned short*)Cout;
#pragma unroll
          for (int r = 0; r < 4; r++)
            Cb[(((size_t)(s * BATCH + b_) * HB + h) * NSEQ + (n + r)) * DHD + dh] =
                f2bf(acc[i][j][r]);
        }
      } else {
        float bb = bias ? bias[col] : 0.f;
        float* Cf = (float*)Cout;
#pragma unroll
        for (int r = 0; r < 4; r++)
          Cf[(size_t)(row + r) * Dn + col] = acc[i][j][r] + bb;
      }
    }
  }
}

// ---------------------------------------------------------------------------
// RoPE (halves convention) + RMSNorm on q,k IN-PLACE on qkvb[s][b][h][n][72].
// One block per (b,n). Trig hoisted across sel (q,k share angles); per-head
// RMS reduce parallelized 4 lanes/head x 2 waves (one per sel) + shfl.
// Q (sel=0) is additionally pre-scaled by 72^-0.5*log2(e) so flash_attn's
// softmax is exp2(S) directly (exact fp32 multiply before bf16 rounding).
// ---------------------------------------------------------------------------
__global__ __launch_bounds__(256) void rope_rms(
    unsigned short* __restrict__ qkvb,
    const float* __restrict__ qw, const float* __restrict__ kw) {
  const int blk = blockIdx.x;
  const int b = blk >> 11;
  const int n = blk & 2047;
  const int tid = threadIdx.x;

  __shared__ float sv[2][CDIM];
  __shared__ float srsq[2][HB];

  const float nf = (float)n;
  const float l2t_over_half = 13.287712379549449f / 36.0f;  // log2(10000)/36
  const float scale2 = 0.17002329230297715f;                // 72^-0.5 * log2(e)

  for (int e = tid; e < CDIM; e += 256) {
    int h  = e / DHD;
    int dh = e - h * DHD;
    int i  = (dh < 36) ? dh : dh - 36;
    float inv_freq = exp2f(-l2t_over_half * (float)i);
    float ang = nf * inv_freq;
    float sn, cs;
    __sincosf(ang, &sn, &cs);
#pragma unroll
    for (int sel = 0; sel < 2; sel++) {
      size_t ah = (((size_t)(sel * BATCH + b) * HB + h) * NSEQ + n) * DHD;
      float x1 = bf2f(qkvb[ah + i]);
      float x2 = bf2f(qkvb[ah + i + 36]);
      sv[sel][e] = (dh < 36) ? (x1 * cs - x2 * sn) : (x2 * cs + x1 * sn);
    }
  }
  __syncthreads();
  if (tid < 128) {   // wave0: sel=0, wave1: sel=1; 4 lanes per head
    int sel = tid >> 6;
    int h = (tid & 63) >> 2, p = tid & 3;
    float s = 0.f;
#pragma unroll
    for (int d = 0; d < 18; d++) {
      float v = sv[sel][h * DHD + p * 18 + d];
      s += v * v;
    }
    s += __shfl_xor(s, 1);
    s += __shfl_xor(s, 2);
    if (p == 0)
      srsq[sel][h] = rsqrtf(s * (1.0f / 72.0f) + 1e-6f) * (sel ? 1.0f : scale2);
  }
  __syncthreads();
  for (int e = tid; e < CDIM; e += 256) {
    int h  = e / DHD;
    int dh = e - h * DHD;
#pragma unroll
    for (int sel = 0; sel < 2; sel++) {
      const float* wnorm = sel ? kw : qw;
      size_t ah = (((size_t)(sel * BATCH + b) * HB + h) * NSEQ + n) * DHD;
      qkvb[ah + dh] = f2bf(sv[sel][e] * srsq[sel][h] * wnorm[dh]);
    }
  }
}

// ---------------------------------------------------------------------------
// Flash attention, no-max softmax (Q pre-scaled; exp2 never overflows since
// q,k are RMS-normed). Block = 128 q-rows x head x batch; 4 waves x
// (2 fused q-tiles of 16). KV tiles of 64.
// S-phase computes S^T via SWAPPED operands mfma(K, Q): D row = kv, col = q.
// Each lane then holds 4 CONSECUTIVE kv values (quad*4+r) for one q row
// (l16), so P packs as u16x4 -> one ds_write_b64 per (qt,nk): 8 b64 writes
// replace 32 b16 writes. sP matrix/layout and the PV phase are unchanged.
// Pipelined schedule (per tile t, 2 barriers):
//   [pf(t) reads; PV(t) MFMAs]                 <- V(t),P(t) ready at entry
//   M: barrier (V readers done)
//   issue V(t+1) DMA -> sVt ; issue K(t+2) DMA -> sK[t&1]
//   [S(t+1) MFMAs from sK[(t+1)&1]; exp2+pack(t+1) -> sP]  <- hides DMA
//   A: barrier (vmcnt(0) drains V(t+1), K(t+2))
// K double-buffered (issued 1.5 tiles ahead); V single-buffered linear
// [80][64] with both-sides XOR swizzle. Row 72 of V = ones -> row-sum l via
// MFMA; rows 73..79 = 0.
// ---------------------------------------------------------------------------
#define SPW 68    // sP row stride (shorts); 136 B/row, 8-byte aligned rows
__global__ __launch_bounds__(256, 3) void flash_attn(
    const unsigned short* __restrict__ qkvb, const unsigned short* __restrict__ Vt,
    unsigned short* __restrict__ AO) {
  __shared__ __attribute__((aligned(16))) unsigned short sK[2 * 64 * 72];  // 18432 B
  __shared__ __attribute__((aligned(16))) unsigned short sVt[80 * 64];     // 10240 B
  __shared__ __attribute__((aligned(16))) unsigned short sP[128 * SPW];    // 17408 B

  const int tid  = threadIdx.x;
  const int w    = tid >> 6;
  const int lane = tid & 63;
  const int quad = lane >> 4, l16 = lane & 15;
  const int q0 = blockIdx.x * 128;
  const int h = blockIdx.y, b = blockIdx.z;

  const unsigned short* Qb = qkvb + ((size_t)(0 * BATCH + b) * HB + h) * NSEQ * DHD;
  const unsigned short* Kb = qkvb + ((size_t)(1 * BATCH + b) * HB + h) * NSEQ * DHD;
  const unsigned short* Vb = Vt + (size_t)(b * HB + h) * DHD * NSEQ;

  const short8 zs = {0, 0, 0, 0, 0, 0, 0, 0};
  const f32x4 zero = {0.f, 0.f, 0.f, 0.f};

  // staging source pointers; wave issue i = w + 4*j (9 x 1KB per array).
  // K tile is a straight linear copy: LDS short off = c*8 == global short off.
  // V: LDS[dh][cg] <- V[dh][cg ^ (dh&7)]  (inverse swizzle on the source).
  const int vswz = ((lane & 7) ^ (lane >> 3)) * 8;
  const int iw = w;  // wave's issue index base
  const unsigned short* pKn[3];  // next K tile to ISSUE (rolls by 64*72)
  const unsigned short* pVn[3];  // next V tile to ISSUE (rolls by 64)
#pragma unroll
  for (int j = 0; j < 3; j++) {
    int i = iw + 4 * j;
    int ii = (i < 9) ? i : 0;
    pKn[j] = Kb + ii * 512 + lane * 8;
    pVn[j] = Vb + (size_t)(ii * 8 + (lane >> 3)) * NSEQ + vswz;
  }

  // prologue: issue K(0) -> sK[0] and V(0) -> sVt
#pragma unroll
  for (int j = 0; j < 3; j++) {
    int i = iw + 4 * j;
    if (i < 9) {
      gload_lds16(pKn[j], sK + i * 512);
      gload_lds16(pVn[j], sVt + i * 512);
    }
  }

  // ones row (d=72) and zero rows (73..79) of V; staging never touches them
  for (int e = tid; e < 512; e += 256)
    sVt[72 * 64 + e] = (e < 64) ? (unsigned short)0x3F80 : (unsigned short)0;

  // Q fragments: 2 q-tiles per wave, rows q0 + w*32 + qt*16 + l16
  short8 aq[2][3];
#pragma unroll
  for (int qt = 0; qt < 2; qt++) {
    const unsigned short* qrow = Qb + (size_t)(q0 + w * 32 + qt * 16 + l16) * DHD;
    aq[qt][0] = *(const short8*)(qrow + quad * 8);
    aq[qt][1] = *(const short8*)(qrow + 32 + quad * 8);
    aq[qt][2] = (quad == 0) ? *(const short8*)(qrow + 64) : zs;
  }

  f32x4 o[2][5];
#pragma unroll
  for (int qt = 0; qt < 2; qt++)
#pragma unroll
    for (int nb = 0; nb < 5; nb++) o[qt][nb] = zero;

  // S-phase + pack for one KV tile from the given sK buffer (both q-tiles;
  // each K fragment read once). SWAPPED operands: D = S^T (row=kv, col=q),
  // so each lane packs 4 consecutive kv as one b64 write to its q-row.
  auto sphase_pack = [&](const unsigned short* sKb) {
    f32x4 st[2][4];
    __builtin_amdgcn_s_setprio(1);
#pragma unroll
    for (int nk = 0; nk < 4; nk++) {
      const unsigned short* kr = sKb + (nk * 16 + l16) * 72;
      short8 kf0 = *(const short8*)(kr + quad * 8);
      short8 kf1 = *(const short8*)(kr + 32 + quad * 8);
      short8 kf2 = *(const short8*)(kr + 64);  // uniform; bogus k-slots masked by aq[2]=0
      f32x4 s0 = zero, s1 = zero;
      s0 = __builtin_amdgcn_mfma_f32_16x16x32_bf16(kf0, aq[0][0], s0, 0, 0, 0);
      s1 = __builtin_amdgcn_mfma_f32_16x16x32_bf16(kf0, aq[1][0], s1, 0, 0, 0);
      s0 = __builtin_amdgcn_mfma_f32_16x16x32_bf16(kf1, aq[0][1], s0, 0, 0, 0);
      s1 = __builtin_amdgcn_mfma_f32_16x16x32_bf16(kf1, aq[1][1], s1, 0, 0, 0);
      s0 = __builtin_amdgcn_mfma_f32_16x16x32_bf16(kf2, aq[0][2], s0, 0, 0, 0);
      s1 = __builtin_amdgcn_mfma_f32_16x16x32_bf16(kf2, aq[1][2], s1, 0, 0, 0);
      st[0][nk] = s0;
      st[1][nk] = s1;
    }
    __builtin_amdgcn_s_setprio(0);
    // P = exp2(S^T) -> bf16 x4 -> one ds_write_b64 per (qt,nk).
    // Row = qt*64 + w*16 + l16 (wave-local), cols nk*16 + quad*4 + r.
#pragma unroll
    for (int qt = 0; qt < 2; qt++) {
      unsigned short* prow = sP + (qt * 64 + w * 16 + l16) * SPW + quad * 4;
#pragma unroll
      for (int nk = 0; nk < 4; nk++) {
        u16x4 pr;
#pragma unroll
        for (int r = 0; r < 4; r++) pr[r] = f2bf_ru(exp2f(st[qt][nk][r]));
        *(u16x4*)(prow + nk * 16) = pr;
      }
    }
  };

  // PV for the current tile: each V fragment read once, feeds both q-tiles.
  auto pv_phase = [&]() {
    __builtin_amdgcn_s_setprio(1);
#pragma unroll
    for (int kb = 0; kb < 2; kb++) {
      short8 pf0 = *(const short8*)(sP + (w * 16 + l16) * SPW + kb * 32 + quad * 8);
      short8 pf1 = *(const short8*)(sP + (64 + w * 16 + l16) * SPW + kb * 32 + quad * 8);
#pragma unroll
      for (int nb = 0; nb < 5; nb++) {
        short8 vf = *(const short8*)(sVt + (nb * 16 + l16) * 64 +
                                     ((kb * 32 + quad * 8) ^ ((l16 & 7) * 8)));
        o[0][nb] = __builtin_amdgcn_mfma_f32_16x16x32_bf16(pf0, vf, o[0][nb], 0, 0, 0);
        o[1][nb] = __builtin_amdgcn_mfma_f32_16x16x32_bf16(pf1, vf, o[1][nb], 0, 0, 0);
      }
    }
    __builtin_amdgcn_s_setprio(0);
  };

  __syncthreads();   // drain K(0), V(0)

  // issue K(1) -> sK[1]
#pragma unroll
  for (int j = 0; j < 3; j++) {
    int i = iw + 4 * j;
    if (i < 9) gload_lds16(pKn[j] + 64 * 72, sK + 4608 + i * 512);
    pKn[j] += 2 * 64 * 72;   // next K issue = K(2)
  }

  sphase_pack(sK);           // S(0) + pack(0) from sK[0]
  __syncthreads();           // drain K(1)

  for (int t = 0; t < 32; t++) {
    pv_phase();              // PV(t): reads sVt=V(t), sP=P(t)

    if (t < 31) {
      __syncthreads();       // M: all V(t)/P(t) reads done

      // issue V(t+1) -> sVt
#pragma unroll
      for (int j = 0; j < 3; j++) {
        int i = iw + 4 * j;
        if (i < 9) gload_lds16(pVn[j] + 64, sVt + i * 512);
        pVn[j] += 64;
      }
      // issue K(t+2) -> sK[t&1] (its last reader S(t) finished last tile)
      if (t < 30) {
#pragma unroll
        for (int j = 0; j < 3; j++) {
          int i = iw + 4 * j;
          if (i < 9) gload_lds16(pKn[j], sK + (t & 1) * 4608 + i * 512);
          pKn[j] += 64 * 72;
        }
      }

      sphase_pack(sK + ((t + 1) & 1) * 4608);  // S(t+1) + pack(t+1), hides DMA
      __syncthreads();       // A: vmcnt(0) drains V(t+1), K(t+2)
    }
  }

  // epilogue: l sits at dh=72 (nb=4, l16=8); broadcast within quad, normalize
#pragma unroll
  for (int qt = 0; qt < 2; qt++) {
    float inv[4];
#pragma unroll
    for (int r = 0; r < 4; r++)
      inv[r] = 1.0f / __shfl(o[qt][4][r], (quad << 4) + 8, 64);
    const int qrow = q0 + w * 32 + qt * 16 + quad * 4;
#pragma unroll
    for (int nb = 0; nb < 5; nb++) {
      int dh = nb * 16 + l16;
      if (dh < DHD) {
#pragma unroll
        for (int r = 0; r < 4; r++)
          AO[((size_t)b * NSEQ + qrow + r) * CDIM + h * DHD + dh] =
              f2bf(o[qt][nb][r] * inv[r]);
      }
    }
  }
}

// ---------------------------------------------------------------------------
extern "C" void kernel_launch(void* const* d_in, const int* in_sizes, int n_in,
                              void* d_out, int out_size, void* d_ws, size_t ws_size,
                              hipStream_t stream) {
  const float* x      = (const float*)d_in[0];
  const float* w_qkv  = (const float*)d_in[1];
  const float* w_proj = (const float*)d_in[2];
  const float* b_proj = (const float*)d_in[3];
  const float* qnw    = (const float*)d_in[4];
  const float* knw    = (const float*)d_in[5];
  float* out = (float*)d_out;

  char* ws = (char*)d_ws;
  // layout (bytes): xb 18.9M | wqkvb 8.0M | wprojb 2.7M | qkvb 37.7M | Vt 18.9M
  // AO aliases xb (xb dead after gemm1). Total 86.1 MB.
  unsigned short* xb    = (unsigned short*)(ws);
  unsigned short* wqkvb = (unsigned short*)(ws + 18874368);
  unsigned short* wprojb= (unsigned short*)(ws + 26836992);
  unsigned short* qkvb  = (unsigned short*)(ws + 29491200);
  unsigned short* Vt    = (unsigned short*)(ws + 67239936);
  unsigned short* AO    = xb;

  cvt_bf16<<<dim3((CVT_CHUNKS + 255) / 256), 256, 0, stream>>>(
      x, w_qkv, w_proj, xb, wqkvb, wprojb);
  gemm_bt<1><<<dim3(D3 / 128, NT / 128), 256, 0, stream>>>(
      xb, wqkvb, nullptr, qkvb, Vt, NT, D3, CDIM);
  rope_rms<<<dim3(NT), 256, 0, stream>>>(qkvb, qnw, knw);
  flash_attn<<<dim3(NSEQ / 128, HB, BATCH), 256, 0, stream>>>(qkvb, Vt, AO);
  gemm_bt<0><<<dim3(CDIM / 128, NT / 128), 256, 0, stream>>>(
      AO, wprojb, b_proj, out, nullptr, NT, CDIM, CDIM);
}

// Round 5
// 393.824 us; speedup vs baseline: 1.1987x; 1.0049x over previous
//
#include <hip/hip_runtime.h>
#include <stdint.h>

// Problem constants
#define BATCH 4
#define NSEQ  2048
#define CDIM  1152
#define HB    16
#define DHD   72
#define D3    3456
#define NT    8192    // BATCH*NSEQ

typedef __attribute__((ext_vector_type(8))) short short8;       // 8 bf16 (4 VGPRs)
typedef __attribute__((ext_vector_type(8))) unsigned short u16x8;
typedef __attribute__((ext_vector_type(4))) unsigned short u16x4;
typedef __attribute__((ext_vector_type(2))) unsigned int u32x2;
typedef __attribute__((ext_vector_type(4))) float f32x4;

__device__ __forceinline__ float bf2f(unsigned short u) {
  return __uint_as_float(((unsigned)u) << 16);
}
__device__ __forceinline__ unsigned short f2bf(float f) {
  unsigned u = __float_as_uint(f);
  u += 0x7FFF + ((u >> 16) & 1);   // RNE
  return (unsigned short)(u >> 16);
}
// packed 2xf32 -> 2xbf16 (RNE) in one instruction (T12 recipe; no builtin)
__device__ __forceinline__ unsigned pkbf(float lo, float hi) {
  unsigned r;
  asm("v_cvt_pk_bf16_f32 %0, %1, %2" : "=v"(r) : "v"(lo), "v"(hi));
  return r;
}

// async 16B global->LDS copy: per-lane global addr, LDS dest = wave-uniform base + lane*16
__device__ __forceinline__ void gload_lds16(const unsigned short* g, unsigned short* l) {
  __builtin_amdgcn_global_load_lds(
      (const __attribute__((address_space(1))) void*)g,
      (__attribute__((address_space(3))) void*)l, 16, 0, 0);
}

// ---------------------------------------------------------------------------
// fp32 -> bf16 conversion prepass for x, w_qkv, w_proj (memory-bound).
// ---------------------------------------------------------------------------
#define XN    ((size_t)NT * CDIM)        // 9,437,184
#define WQN   ((size_t)D3 * CDIM)        // 3,981,312
#define WPN   ((size_t)CDIM * CDIM)      // 1,327,104
#define CVT_CHUNKS ((XN + WQN + WPN) / 4)  // 3,686,400 float4 chunks

__global__ __launch_bounds__(256) void cvt_bf16(
    const float* __restrict__ x, const float* __restrict__ wq,
    const float* __restrict__ wp, unsigned short* __restrict__ xb,
    unsigned short* __restrict__ wqb, unsigned short* __restrict__ wpb) {
  size_t c = (size_t)blockIdx.x * 256 + threadIdx.x;
  if (c >= CVT_CHUNKS) return;
  const float* src;
  unsigned short* dst;
  size_t e = c * 4;
  if (e < XN) { src = x + e; dst = xb + e; }
  else if (e < XN + WQN) { src = wq + (e - XN); dst = wqb + (e - XN); }
  else { src = wp + (e - XN - WQN); dst = wpb + (e - XN - WQN); }
  f32x4 v = *(const f32x4*)src;
  u16x4 r;
#pragma unroll
  for (int i = 0; i < 4; i++) r[i] = f2bf(v[i]);
  *(u16x4*)dst = r;
}

// ---------------------------------------------------------------------------
// GEMM-BT (bf16 in): C[M,Dn] = A[M,K]*Bt[Dn,K]^T (+bias), fp32 acc.
// BM=BN=128, BK=32, 256 thr = 4 waves (2x2 of 64x64), 16x16x32 MFMA,
// global_load_lds width-16 staging (m97 structure). XCD-bijective block
// swizzle (grids are multiples of 8).
// SCATTER=1: bf16 scatter: Q,K -> qkvb[s][b][h][n][72], V -> Vt[b][h][dh][n].
// SCATTER=0: fp32 out + fp32 bias.
// ---------------------------------------------------------------------------
template <int SCATTER>
__global__ __launch_bounds__(256) void gemm_bt(
    const unsigned short* __restrict__ A, const unsigned short* __restrict__ Bt,
    const float* __restrict__ bias, void* __restrict__ Cout,
    unsigned short* __restrict__ Vt, int M, int Dn, int K) {
  __shared__ __attribute__((aligned(16))) unsigned short sA[128 * 32];
  __shared__ __attribute__((aligned(16))) unsigned short sB[128 * 32];

  const int tid  = threadIdx.x;
  const int lane = tid & 63;
  const int w    = tid >> 6;
  const int wm   = w >> 1, wn = w & 1;
  const int quad = lane >> 4, l16 = lane & 15;

  // XCD-aware bijective swizzle: nwg % 8 == 0 for both call sites.
  const int gx  = gridDim.x;
  const int nwg = gx * gridDim.y;
  const int lb  = blockIdx.y * gx + blockIdx.x;
  const int swz = (lb & 7) * (nwg >> 3) + (lb >> 3);
  const int m0 = (swz / gx) * 128, n0 = (swz % gx) * 128;

  // staging addresses: wave w copies 16-row chunks {2w,2w+1} of A and B.
  // chunk ck: lane i -> row ck*16 + i/4, col (i%4)*8  (1024 B contiguous LDS)
  const int srow = (lane >> 2);
  const int scol = (lane & 3) << 3;

  const f32x4 zero = {0.f, 0.f, 0.f, 0.f};
  f32x4 acc[4][4];
#pragma unroll
  for (int i = 0; i < 4; i++)
#pragma unroll
    for (int j = 0; j < 4; j++) acc[i][j] = zero;

  for (int kt = 0; kt < K; kt += 32) {
#pragma unroll
    for (int i = 0; i < 2; i++) {
      int ck = w * 2 + i;
      gload_lds16(A + (size_t)(m0 + ck * 16 + srow) * K + kt + scol, sA + ck * 512);
      gload_lds16(Bt + (size_t)(n0 + ck * 16 + srow) * K + kt + scol, sB + ck * 512);
    }
    __syncthreads();

    short8 a[4], b[4];
#pragma unroll
    for (int i = 0; i < 4; i++)
      a[i] = *(const short8*)(sA + (wm * 64 + i * 16 + l16) * 32 + quad * 8);
#pragma unroll
    for (int j = 0; j < 4; j++)
      b[j] = *(const short8*)(sB + (wn * 64 + j * 16 + l16) * 32 + quad * 8);

#pragma unroll
    for (int i = 0; i < 4; i++)
#pragma unroll
      for (int j = 0; j < 4; j++)
        acc[i][j] = __builtin_amdgcn_mfma_f32_16x16x32_bf16(a[i], b[j], acc[i][j], 0, 0, 0);
    __syncthreads();
  }

  // epilogue: D row = quad*4+r, col = lane&15
#pragma unroll
  for (int i = 0; i < 4; i++) {
    int row = m0 + wm * 64 + i * 16 + quad * 4;
#pragma unroll
    for (int j = 0; j < 4; j++) {
      int col = n0 + wn * 64 + j * 16 + l16;
      if (SCATTER) {
        int s  = col / CDIM;
        int rm = col - s * CDIM;
        int h  = rm / DHD;
        int dh = rm - h * DHD;
        int b_ = row >> 11;           // rows of 4 never straddle the 2048 bdry
        int n  = row & 2047;
        if (s == 2) {
#pragma unroll
          for (int r = 0; r < 4; r++)
            Vt[((size_t)(b_ * HB + h) * DHD + dh) * NSEQ + n + r] = f2bf(acc[i][j][r]);
        } else {
          unsigned short* Cb = (unsigned short*)Cout;
#pragma unroll
          for (int r = 0; r < 4; r++)
            Cb[(((size_t)(s * BATCH + b_) * HB + h) * NSEQ + (n + r)) * DHD + dh] =
                f2bf(acc[i][j][r]);
        }
      } else {
        float bb = bias ? bias[col] : 0.f;
        float* Cf = (float*)Cout;
#pragma unroll
        for (int r = 0; r < 4; r++)
          Cf[(size_t)(row + r) * Dn + col] = acc[i][j][r] + bb;
      }
    }
  }
}

// ---------------------------------------------------------------------------
// RoPE (halves convention) + RMSNorm on q,k IN-PLACE on qkvb[s][b][h][n][72].
// One block per (b,n). Trig hoisted across sel (q,k share angles); per-head
// RMS reduce parallelized 4 lanes/head x 2 waves (one per sel) + shfl.
// Q (sel=0) is additionally pre-scaled by 72^-0.5*log2(e) so flash_attn's
// softmax is exp2(S) directly (exact fp32 multiply before bf16 rounding).
// ---------------------------------------------------------------------------
__global__ __launch_bounds__(256) void rope_rms(
    unsigned short* __restrict__ qkvb,
    const float* __restrict__ qw, const float* __restrict__ kw) {
  const int blk = blockIdx.x;
  const int b = blk >> 11;
  const int n = blk & 2047;
  const int tid = threadIdx.x;

  __shared__ float sv[2][CDIM];
  __shared__ float srsq[2][HB];

  const float nf = (float)n;
  const float l2t_over_half = 13.287712379549449f / 36.0f;  // log2(10000)/36
  const float scale2 = 0.17002329230297715f;                // 72^-0.5 * log2(e)

  for (int e = tid; e < CDIM; e += 256) {
    int h  = e / DHD;
    int dh = e - h * DHD;
    int i  = (dh < 36) ? dh : dh - 36;
    float inv_freq = exp2f(-l2t_over_half * (float)i);
    float ang = nf * inv_freq;
    float sn, cs;
    __sincosf(ang, &sn, &cs);
#pragma unroll
    for (int sel = 0; sel < 2; sel++) {
      size_t ah = (((size_t)(sel * BATCH + b) * HB + h) * NSEQ + n) * DHD;
      float x1 = bf2f(qkvb[ah + i]);
      float x2 = bf2f(qkvb[ah + i + 36]);
      sv[sel][e] = (dh < 36) ? (x1 * cs - x2 * sn) : (x2 * cs + x1 * sn);
    }
  }
  __syncthreads();
  if (tid < 128) {   // wave0: sel=0, wave1: sel=1; 4 lanes per head
    int sel = tid >> 6;
    int h = (tid & 63) >> 2, p = tid & 3;
    float s = 0.f;
#pragma unroll
    for (int d = 0; d < 18; d++) {
      float v = sv[sel][h * DHD + p * 18 + d];
      s += v * v;
    }
    s += __shfl_xor(s, 1);
    s += __shfl_xor(s, 2);
    if (p == 0)
      srsq[sel][h] = rsqrtf(s * (1.0f / 72.0f) + 1e-6f) * (sel ? 1.0f : scale2);
  }
  __syncthreads();
  for (int e = tid; e < CDIM; e += 256) {
    int h  = e / DHD;
    int dh = e - h * DHD;
#pragma unroll
    for (int sel = 0; sel < 2; sel++) {
      const float* wnorm = sel ? kw : qw;
      size_t ah = (((size_t)(sel * BATCH + b) * HB + h) * NSEQ + n) * DHD;
      qkvb[ah + dh] = f2bf(sv[sel][e] * srsq[sel][h] * wnorm[dh]);
    }
  }
}

// ---------------------------------------------------------------------------
// Flash attention, no-max softmax (Q pre-scaled; exp2 never overflows since
// q,k are RMS-normed). Block = 128 q-rows x head x batch; 4 waves x
// (2 fused q-tiles of 16). KV tiles of 64.
// S-phase computes S^T via SWAPPED operands mfma(K, Q): D row = kv, col = q.
// Each lane holds 4 consecutive kv for one q row -> v_cvt_pk_bf16_f32 pairs
// -> one ds_write_b64 per (qt,nk).
// LDS budget cut for 4 blocks/CU residency (35840 B x 4 = 143 KB <= 160 KB):
//   sK single-buffered [64][72] (schedule-neutral per R2 vs R3 A/B);
//   sVt [80][64], 16B-unit XOR swizzle (unit ^= dh&7), ones row 72, 0 rows 73+;
//   sP  [128][64] unpadded, same 16B-unit XOR swizzle (unit ^= qrow&7):
//       b64 writes stay 8B-aligned, 4 lanes/bank = b64 minimum (conflict-free),
//       b128 reads swizzle-spread like sVt.
// Schedule per tile (2 barriers):
//   S(t)+pack(t) [reads sK, writes sP]
//   F barrier (drains V(t) DMA; sK readers done)
//   issue K(t+1) -> sK
//   PV(t) [reads sVt, sP]
//   E barrier (drains K(t+1); sVt readers done)
//   issue V(t+1) -> sVt
// ---------------------------------------------------------------------------
__global__ __launch_bounds__(256, 4) void flash_attn(
    const unsigned short* __restrict__ qkvb, const unsigned short* __restrict__ Vt,
    unsigned short* __restrict__ AO) {
  __shared__ __attribute__((aligned(16))) unsigned short sK[64 * 72];    //  9216 B
  __shared__ __attribute__((aligned(16))) unsigned short sVt[80 * 64];   // 10240 B
  __shared__ __attribute__((aligned(16))) unsigned short sP[128 * 64];   // 16384 B

  const int tid  = threadIdx.x;
  const int w    = tid >> 6;
  const int lane = tid & 63;
  const int quad = lane >> 4, l16 = lane & 15;
  const int s7   = l16 & 7;
  const int q0 = blockIdx.x * 128;
  const int h = blockIdx.y, b = blockIdx.z;

  const unsigned short* Qb = qkvb + ((size_t)(0 * BATCH + b) * HB + h) * NSEQ * DHD;
  const unsigned short* Kb = qkvb + ((size_t)(1 * BATCH + b) * HB + h) * NSEQ * DHD;
  const unsigned short* Vb = Vt + (size_t)(b * HB + h) * DHD * NSEQ;

  const short8 zs = {0, 0, 0, 0, 0, 0, 0, 0};
  const f32x4 zero = {0.f, 0.f, 0.f, 0.f};

  // staging source pointers; wave issue i = w + 4*j (9 x 1KB per array).
  // K tile is a straight linear copy: LDS short off = c*8 == global short off.
  // V: LDS[dh][cg] <- V[dh][cg ^ (dh&7)]  (inverse swizzle on the source).
  const int vswz = ((lane & 7) ^ (lane >> 3)) * 8;
  const unsigned short* pKn[3];  // next K tile to ISSUE (rolls by 64*72)
  const unsigned short* pVn[3];  // next V tile to ISSUE (rolls by 64)
#pragma unroll
  for (int j = 0; j < 3; j++) {
    int i = w + 4 * j;
    int ii = (i < 9) ? i : 0;
    pKn[j] = Kb + ii * 512 + lane * 8;
    pVn[j] = Vb + (size_t)(ii * 8 + (lane >> 3)) * NSEQ + vswz;
  }

  // prologue: issue K(0) -> sK and V(0) -> sVt
#pragma unroll
  for (int j = 0; j < 3; j++) {
    int i = w + 4 * j;
    if (i < 9) {
      gload_lds16(pKn[j], sK + i * 512);
      gload_lds16(pVn[j], sVt + i * 512);
      pKn[j] += 64 * 72;
      pVn[j] += 64;
    }
  }

  // ones row (d=72) and zero rows (73..79) of V; staging never touches them
  for (int e = tid; e < 512; e += 256)
    sVt[72 * 64 + e] = (e < 64) ? (unsigned short)0x3F80 : (unsigned short)0;

  // Q fragments: 2 q-tiles per wave, rows q0 + w*32 + qt*16 + l16
  short8 aq[2][3];
#pragma unroll
  for (int qt = 0; qt < 2; qt++) {
    const unsigned short* qrow = Qb + (size_t)(q0 + w * 32 + qt * 16 + l16) * DHD;
    aq[qt][0] = *(const short8*)(qrow + quad * 8);
    aq[qt][1] = *(const short8*)(qrow + 32 + quad * 8);
    aq[qt][2] = (quad == 0) ? *(const short8*)(qrow + 64) : zs;
  }

  f32x4 o[2][5];
#pragma unroll
  for (int qt = 0; qt < 2; qt++)
#pragma unroll
    for (int nb = 0; nb < 5; nb++) o[qt][nb] = zero;

  // S-phase + pack (both q-tiles; each K fragment read once). SWAPPED
  // operands: D = S^T (row=kv, col=q); lane packs 4 consecutive kv with
  // 2 cvt_pk -> one b64 write into swizzled sP.
  auto sphase_pack = [&]() {
    f32x4 st[2][4];
    __builtin_amdgcn_s_setprio(1);
#pragma unroll
    for (int nk = 0; nk < 4; nk++) {
      const unsigned short* kr = sK + (nk * 16 + l16) * 72;
      short8 kf0 = *(const short8*)(kr + quad * 8);
      short8 kf1 = *(const short8*)(kr + 32 + quad * 8);
      short8 kf2 = *(const short8*)(kr + 64);  // uniform; bogus k-slots masked by aq[2]=0
      f32x4 s0 = zero, s1 = zero;
      s0 = __builtin_amdgcn_mfma_f32_16x16x32_bf16(kf0, aq[0][0], s0, 0, 0, 0);
      s1 = __builtin_amdgcn_mfma_f32_16x16x32_bf16(kf0, aq[1][0], s1, 0, 0, 0);
      s0 = __builtin_amdgcn_mfma_f32_16x16x32_bf16(kf1, aq[0][1], s0, 0, 0, 0);
      s1 = __builtin_amdgcn_mfma_f32_16x16x32_bf16(kf1, aq[1][1], s1, 0, 0, 0);
      s0 = __builtin_amdgcn_mfma_f32_16x16x32_bf16(kf2, aq[0][2], s0, 0, 0, 0);
      s1 = __builtin_amdgcn_mfma_f32_16x16x32_bf16(kf2, aq[1][2], s1, 0, 0, 0);
      st[0][nk] = s0;
      st[1][nk] = s1;
    }
    __builtin_amdgcn_s_setprio(0);
    // P = exp2(S^T): row = qt*64 + w*16 + l16, colshort = nk*16 + quad*4 + r.
    // Swizzled addr: row*64 + ((colshort>>3)^(row&7))*8 + (colshort&7).
#pragma unroll
    for (int qt = 0; qt < 2; qt++) {
      unsigned short* prow = sP + (qt * 64 + w * 16 + l16) * 64 + (quad & 1) * 4;
#pragma unroll
      for (int nk = 0; nk < 4; nk++) {
        int uoff = ((nk * 2 + (quad >> 1)) ^ s7) << 3;
        u32x2 pr;
        pr[0] = pkbf(exp2f(st[qt][nk][0]), exp2f(st[qt][nk][1]));
        pr[1] = pkbf(exp2f(st[qt][nk][2]), exp2f(st[qt][nk][3]));
        *(u32x2*)(prow + uoff) = pr;
      }
    }
  };

  // PV for the current tile: each V fragment read once, feeds both q-tiles.
  auto pv_phase = [&]() {
    __builtin_amdgcn_s_setprio(1);
#pragma unroll
    for (int kb = 0; kb < 2; kb++) {
      const unsigned short* pp =
          sP + (w * 16 + l16) * 64 + (((kb * 4 + quad) ^ s7) << 3);
      short8 pf0 = *(const short8*)pp;
      short8 pf1 = *(const short8*)(pp + 64 * 64);  // qt=1 rows (+64: same row&7)
#pragma unroll
      for (int nb = 0; nb < 5; nb++) {
        short8 vf = *(const short8*)(sVt + (nb * 16 + l16) * 64 +
                                     (((kb * 4 + quad) ^ s7) << 3));
        o[0][nb] = __builtin_amdgcn_mfma_f32_16x16x32_bf16(pf0, vf, o[0][nb], 0, 0, 0);
        o[1][nb] = __builtin_amdgcn_mfma_f32_16x16x32_bf16(pf1, vf, o[1][nb], 0, 0, 0);
      }
    }
    __builtin_amdgcn_s_setprio(0);
  };

  __syncthreads();   // drain K(0), V(0)

  for (int t = 0; t < 32; t++) {
    sphase_pack();           // S(t)+pack(t): reads sK, writes own sP rows

    __syncthreads();         // F: sK readers done; V(t) DMA drained (prev E)

    if (t < 31) {            // issue K(t+1) into sK (readers finished)
#pragma unroll
      for (int j = 0; j < 3; j++) {
        int i = w + 4 * j;
        if (i < 9) { gload_lds16(pKn[j], sK + i * 512); pKn[j] += 64 * 72; }
      }
    }

    pv_phase();              // PV(t): reads sVt=V(t), sP=P(t)

    __syncthreads();         // E: sVt readers done; K(t+1) DMA drained

    if (t < 31) {            // issue V(t+1); drains at next F
#pragma unroll
      for (int j = 0; j < 3; j++) {
        int i = w + 4 * j;
        if (i < 9) { gload_lds16(pVn[j], sVt + i * 512); pVn[j] += 64; }
      }
    }
  }

  // epilogue: l sits at dh=72 (nb=4, l16=8); broadcast within quad, normalize
#pragma unroll
  for (int qt = 0; qt < 2; qt++) {
    float inv[4];
#pragma unroll
    for (int r = 0; r < 4; r++)
      inv[r] = 1.0f / __shfl(o[qt][4][r], (quad << 4) + 8, 64);
    const int qrow = q0 + w * 32 + qt * 16 + quad * 4;
#pragma unroll
    for (int nb = 0; nb < 5; nb++) {
      int dh = nb * 16 + l16;
      if (dh < DHD) {
#pragma unroll
        for (int r = 0; r < 4; r++)
          AO[((size_t)b * NSEQ + qrow + r) * CDIM + h * DHD + dh] =
              f2bf(o[qt][nb][r] * inv[r]);
      }
    }
  }
}

// ---------------------------------------------------------------------------
extern "C" void kernel_launch(void* const* d_in, const int* in_sizes, int n_in,
                              void* d_out, int out_size, void* d_ws, size_t ws_size,
                              hipStream_t stream) {
  const float* x      = (const float*)d_in[0];
  const float* w_qkv  = (const float*)d_in[1];
  const float* w_proj = (const float*)d_in[2];
  const float* b_proj = (const float*)d_in[3];
  const float* qnw    = (const float*)d_in[4];
  const float* knw    = (const float*)d_in[5];
  float* out = (float*)d_out;

  char* ws = (char*)d_ws;
  // layout (bytes): xb 18.9M | wqkvb 8.0M | wprojb 2.7M | qkvb 37.7M | Vt 18.9M
  // AO aliases xb (xb dead after gemm1). Total 86.1 MB.
  unsigned short* xb    = (unsigned short*)(ws);
  unsigned short* wqkvb = (unsigned short*)(ws + 18874368);
  unsigned short* wprojb= (unsigned short*)(ws + 26836992);
  unsigned short* qkvb  = (unsigned short*)(ws + 29491200);
  unsigned short* Vt    = (unsigned short*)(ws + 67239936);
  unsigned short* AO    = xb;

  cvt_bf16<<<dim3((CVT_CHUNKS + 255) / 256), 256, 0, stream>>>(
      x, w_qkv, w_proj, xb, wqkvb, wprojb);
  gemm_bt<1><<<dim3(D3 / 128, NT / 128), 256, 0, stream>>>(
      xb, wqkvb, nullptr, qkvb, Vt, NT, D3, CDIM);
  rope_rms<<<dim3(NT), 256, 0, stream>>>(qkvb, qnw, knw);
  flash_attn<<<dim3(NSEQ / 128, HB, BATCH), 256, 0, stream>>>(qkvb, Vt, AO);
  gemm_bt<0><<<dim3(CDIM / 128, NT / 128), 256, 0, stream>>>(
      AO, wprojb, b_proj, out, nullptr, NT, CDIM, CDIM);
}

// Round 7
// 367.627 us; speedup vs baseline: 1.2841x; 1.0713x over previous
//
#include <hip/hip_runtime.h>
#include <stdint.h>

// Problem constants
#define BATCH 4
#define NSEQ  2048
#define CDIM  1152
#define HB    16
#define DHD   72
#define D3    3456
#define NT    8192    // BATCH*NSEQ

typedef __attribute__((ext_vector_type(8))) short short8;       // 8 bf16 (4 VGPRs)
typedef __attribute__((ext_vector_type(8))) unsigned short u16x8;
typedef __attribute__((ext_vector_type(4))) unsigned short u16x4;
typedef __attribute__((ext_vector_type(2))) unsigned int u32x2;
typedef __attribute__((ext_vector_type(4))) float f32x4;

__device__ __forceinline__ float bf2f(unsigned short u) {
  return __uint_as_float(((unsigned)u) << 16);
}
__device__ __forceinline__ unsigned short f2bf(float f) {
  unsigned u = __float_as_uint(f);
  u += 0x7FFF + ((u >> 16) & 1);   // RNE
  return (unsigned short)(u >> 16);
}
// packed 2xf32 -> 2xbf16 (RNE) in one instruction (T12 recipe; no builtin)
__device__ __forceinline__ unsigned pkbf(float lo, float hi) {
  unsigned r;
  asm("v_cvt_pk_bf16_f32 %0, %1, %2" : "=v"(r) : "v"(lo), "v"(hi));
  return r;
}

// async 16B global->LDS copy: per-lane global addr, LDS dest = wave-uniform base + lane*16
__device__ __forceinline__ void gload_lds16(const unsigned short* g, unsigned short* l) {
  __builtin_amdgcn_global_load_lds(
      (const __attribute__((address_space(1))) void*)g,
      (__attribute__((address_space(3))) void*)l, 16, 0, 0);
}

// ---------------------------------------------------------------------------
// fp32 -> bf16 conversion prepass for x, w_qkv, w_proj (memory-bound).
// ---------------------------------------------------------------------------
#define XN    ((size_t)NT * CDIM)        // 9,437,184
#define WQN   ((size_t)D3 * CDIM)        // 3,981,312
#define WPN   ((size_t)CDIM * CDIM)      // 1,327,104
#define CVT_CHUNKS ((XN + WQN + WPN) / 4)  // 3,686,400 float4 chunks

__global__ __launch_bounds__(256) void cvt_bf16(
    const float* __restrict__ x, const float* __restrict__ wq,
    const float* __restrict__ wp, unsigned short* __restrict__ xb,
    unsigned short* __restrict__ wqb, unsigned short* __restrict__ wpb) {
  size_t c = (size_t)blockIdx.x * 256 + threadIdx.x;
  if (c >= CVT_CHUNKS) return;
  const float* src;
  unsigned short* dst;
  size_t e = c * 4;
  if (e < XN) { src = x + e; dst = xb + e; }
  else if (e < XN + WQN) { src = wq + (e - XN); dst = wqb + (e - XN); }
  else { src = wp + (e - XN - WQN); dst = wpb + (e - XN - WQN); }
  f32x4 v = *(const f32x4*)src;
  u16x4 r;
#pragma unroll
  for (int i = 0; i < 4; i++) r[i] = f2bf(v[i]);
  *(u16x4*)dst = r;
}

// ---------------------------------------------------------------------------
// GEMM-BT (bf16 in): C[M,Dn] = A[M,K]*Bt[Dn,K]^T (+bias), fp32 acc.
// BM=BN=128, BK=64 (18 K-steps for K=1152 -> half the barrier drains of
// BK=32), 256 thr = 4 waves (2x2 of 64x64), 16x16x32 MFMA.
// Staging: global_load_lds width-16, LINEAR LDS dest + INVERSE-SWIZZLED
// per-lane global source; ds_read_b128 applies the same XOR (T21
// both-sides): LDS[r][u] = G[r][u ^ (r&7)], read unit U at row R from
// LDS[R][U ^ (R&7)] -> conflict-free (8 dwords/bank, the b128 minimum).
// Grid mapping: XCD owns an 8-row-tile band, rows-fastest within a column
// (A-band 2.4MB + B-panel 0.3MB stay L2-resident). REQUIRES gridDim.y==64
// and K % 64 == 0 (both call sites: gy = NT/128 = 64, K = 1152).
// SCATTER=1: bf16 scatter: Q,K -> qkvb[s][b][h][n][72], V -> Vt[b][h][dh][n].
// SCATTER=0: fp32 out + fp32 bias.
// ---------------------------------------------------------------------------
template <int SCATTER>
__global__ __launch_bounds__(256) void gemm_bt(
    const unsigned short* __restrict__ A, const unsigned short* __restrict__ Bt,
    const float* __restrict__ bias, void* __restrict__ Cout,
    unsigned short* __restrict__ Vt, int M, int Dn, int K) {
  __shared__ __attribute__((aligned(16))) unsigned short sA[128 * 64];  // 16 KB
  __shared__ __attribute__((aligned(16))) unsigned short sB[128 * 64];  // 16 KB

  const int tid  = threadIdx.x;
  const int lane = tid & 63;
  const int w    = tid >> 6;
  const int wm   = w >> 1, wn = w & 1;
  const int quad = lane >> 4, l16 = lane & 15;
  const int s7l  = l16 & 7;

  // XCD band mapping: xcd = lb&7 owns row tiles [xcd*8, xcd*8+8) x all cols,
  // iterating the 8 rows fastest (pos&7), then columns (pos>>3).
  const int gx  = gridDim.x;
  const int lb  = blockIdx.y * gx + blockIdx.x;
  const int xcd = lb & 7;
  const int pos = lb >> 3;
  const int m0 = ((xcd << 3) + (pos & 7)) * 128;
  const int n0 = (pos >> 3) * 128;

  // staging: 16 chunks of 8 rows x 64 cols (1 KB); wave w takes ck = 4w+i.
  // lane -> row (lane>>3), source col unit (lane&7)^(lane>>3) [inverse swz].
  const int r8 = lane >> 3;
  const int cu = (lane & 7) ^ r8;
  const unsigned short* gA = A  + (size_t)(m0 + w * 32 + r8) * K + cu * 8;
  const unsigned short* gB = Bt + (size_t)(n0 + w * 32 + r8) * K + cu * 8;

  const f32x4 zero = {0.f, 0.f, 0.f, 0.f};
  f32x4 acc[4][4];
#pragma unroll
  for (int i = 0; i < 4; i++)
#pragma unroll
    for (int j = 0; j < 4; j++) acc[i][j] = zero;

  for (int kt = 0; kt < K; kt += 64) {
#pragma unroll
    for (int i = 0; i < 4; i++) {
      gload_lds16(gA + (size_t)i * 8 * K + kt, sA + (w * 4 + i) * 512);
      gload_lds16(gB + (size_t)i * 8 * K + kt, sB + (w * 4 + i) * 512);
    }
    __syncthreads();

#pragma unroll
    for (int kk = 0; kk < 2; kk++) {
      short8 a[4], b[4];
#pragma unroll
      for (int i = 0; i < 4; i++) {
        a[i] = *(const short8*)(sA + (wm * 64 + i * 16 + l16) * 64 +
                                (((kk * 4 + quad) ^ s7l) << 3));
        b[i] = *(const short8*)(sB + (wn * 64 + i * 16 + l16) * 64 +
                                (((kk * 4 + quad) ^ s7l) << 3));
      }
#pragma unroll
      for (int i = 0; i < 4; i++)
#pragma unroll
        for (int j = 0; j < 4; j++)
          acc[i][j] = __builtin_amdgcn_mfma_f32_16x16x32_bf16(a[i], b[j], acc[i][j], 0, 0, 0);
    }
    __syncthreads();
  }

  // epilogue: D row = quad*4+r, col = lane&15
#pragma unroll
  for (int i = 0; i < 4; i++) {
    int row = m0 + wm * 64 + i * 16 + quad * 4;
#pragma unroll
    for (int j = 0; j < 4; j++) {
      int col = n0 + wn * 64 + j * 16 + l16;
      if (SCATTER) {
        int s  = col / CDIM;
        int rm = col - s * CDIM;
        int h  = rm / DHD;
        int dh = rm - h * DHD;
        int b_ = row >> 11;           // rows of 4 never straddle the 2048 bdry
        int n  = row & 2047;
        if (s == 2) {
#pragma unroll
          for (int r = 0; r < 4; r++)
            Vt[((size_t)(b_ * HB + h) * DHD + dh) * NSEQ + n + r] = f2bf(acc[i][j][r]);
        } else {
          unsigned short* Cb = (unsigned short*)Cout;
#pragma unroll
          for (int r = 0; r < 4; r++)
            Cb[(((size_t)(s * BATCH + b_) * HB + h) * NSEQ + (n + r)) * DHD + dh] =
                f2bf(acc[i][j][r]);
        }
      } else {
        float bb = bias ? bias[col] : 0.f;
        float* Cf = (float*)Cout;
#pragma unroll
        for (int r = 0; r < 4; r++)
          Cf[(size_t)(row + r) * Dn + col] = acc[i][j][r] + bb;
      }
    }
  }
}

// ---------------------------------------------------------------------------
// RoPE (halves convention) + RMSNorm on q,k IN-PLACE on qkvb[s][b][h][n][72].
// One block per (b,n). Vectorized global I/O (u16x8, 16 B/lane) through an
// LDS staging buffer; RoPE applied pair-wise (i, i+36) in-place in LDS
// (each pair owned by exactly one thread). Per-head RMS reduce 4 lanes/head
// x 2 waves + shfl. Q (sel=0) pre-scaled by 72^-0.5*log2(e) so flash_attn's
// softmax is exp2(S) directly. Arithmetic identical to the scalar version.
// ---------------------------------------------------------------------------
__global__ __launch_bounds__(256) void rope_rms(
    unsigned short* __restrict__ qkvb,
    const float* __restrict__ qw, const float* __restrict__ kw) {
  const int blk = blockIdx.x;
  const int b = blk >> 11;
  const int n = blk & 2047;
  const int tid = threadIdx.x;

  __shared__ float sv[2][CDIM];   // 9216 B
  __shared__ float srsq[2][HB];

  const float nf = (float)n;
  const float l2t_over_half = 13.287712379549449f / 36.0f;  // log2(10000)/36
  const float scale2 = 0.17002329230297715f;                // 72^-0.5 * log2(e)

  // Phase 1: vectorized load -> LDS f32. 288 groups of 8 shorts
  // (sel: 144 = 16 heads x 9 units).
  for (int g = tid; g < 288; g += 256) {
    int sel = (g >= 144) ? 1 : 0;
    int gg  = g - sel * 144;
    int h   = gg / 9;
    int u   = gg - h * 9;
    const unsigned short* src =
        qkvb + (((size_t)(sel * BATCH + b) * HB + h) * NSEQ + n) * DHD + u * 8;
    u16x8 v = *(const u16x8*)src;
    float* dst = &sv[sel][h * DHD + u * 8];
#pragma unroll
    for (int r = 0; r < 8; r++) dst[r] = bf2f(v[r]);
  }
  __syncthreads();

  // Phase 2: RoPE pairs (i, i+36) in-place. 2*16*36 = 1152 pairs.
  for (int p = tid; p < 1152; p += 256) {
    int sel = (p >= 576) ? 1 : 0;
    int pp  = p - sel * 576;
    int h   = pp / 36;
    int i   = pp - h * 36;
    float* row = &sv[sel][h * DHD];
    float x1 = row[i], x2 = row[i + 36];
    float ang = nf * exp2f(-l2t_over_half * (float)i);
    float sn, cs;
    __sincosf(ang, &sn, &cs);
    row[i]      = x1 * cs - x2 * sn;
    row[i + 36] = x2 * cs + x1 * sn;
  }
  __syncthreads();

  // Phase 3: per-head RMS. wave0: sel=0, wave1: sel=1; 4 lanes per head.
  if (tid < 128) {
    int sel = tid >> 6;
    int h = (tid & 63) >> 2, p = tid & 3;
    float s = 0.f;
#pragma unroll
    for (int d = 0; d < 18; d++) {
      float v = sv[sel][h * DHD + p * 18 + d];
      s += v * v;
    }
    s += __shfl_xor(s, 1);
    s += __shfl_xor(s, 2);
    if (p == 0)
      srsq[sel][h] = rsqrtf(s * (1.0f / 72.0f) + 1e-6f) * (sel ? 1.0f : scale2);
  }
  __syncthreads();

  // Phase 4: normalize + weight, vectorized write-back.
  for (int g = tid; g < 288; g += 256) {
    int sel = (g >= 144) ? 1 : 0;
    int gg  = g - sel * 144;
    int h   = gg / 9;
    int u   = gg - h * 9;
    float rs = srsq[sel][h];
    const float* wn = (sel ? kw : qw) + u * 8;
    const float* s = &sv[sel][h * DHD + u * 8];
    u16x8 o;
#pragma unroll
    for (int r = 0; r < 8; r++) o[r] = f2bf(s[r] * rs * wn[r]);
    unsigned short* dst =
        qkvb + (((size_t)(sel * BATCH + b) * HB + h) * NSEQ + n) * DHD + u * 8;
    *(u16x8*)dst = o;
  }
}

// ---------------------------------------------------------------------------
// Flash attention, no-max softmax (Q pre-scaled; exp2 never overflows since
// q,k are RMS-normed). Block = 128 q-rows x head x batch; 4 waves x
// (2 fused q-tiles of 16). KV tiles of 64.
// S-phase computes S^T via SWAPPED operands mfma(K, Q): D row = kv, col = q.
// Each lane holds 4 consecutive kv for one q row -> v_cvt_pk_bf16_f32 pairs
// -> one ds_write_b64 per (qt,nk).
// LDS budget cut for 4 blocks/CU residency (35840 B x 4 = 143 KB <= 160 KB):
//   sK single-buffered [64][72];
//   sVt [80][64], 16B-unit XOR swizzle (unit ^= dh&7), ones row 72, 0 rows 73+;
//   sP  [128][64] unpadded, same 16B-unit XOR swizzle (unit ^= qrow&7).
// Schedule per tile (2 barriers): S+pack | F | issue K(t+1) | PV | E |
// issue V(t+1).   [UNCHANGED from R5 -- control for this round]
// ---------------------------------------------------------------------------
__global__ __launch_bounds__(256, 4) void flash_attn(
    const unsigned short* __restrict__ qkvb, const unsigned short* __restrict__ Vt,
    unsigned short* __restrict__ AO) {
  __shared__ __attribute__((aligned(16))) unsigned short sK[64 * 72];    //  9216 B
  __shared__ __attribute__((aligned(16))) unsigned short sVt[80 * 64];   // 10240 B
  __shared__ __attribute__((aligned(16))) unsigned short sP[128 * 64];   // 16384 B

  const int tid  = threadIdx.x;
  const int w    = tid >> 6;
  const int lane = tid & 63;
  const int quad = lane >> 4, l16 = lane & 15;
  const int s7   = l16 & 7;
  const int q0 = blockIdx.x * 128;
  const int h = blockIdx.y, b = blockIdx.z;

  const unsigned short* Qb = qkvb + ((size_t)(0 * BATCH + b) * HB + h) * NSEQ * DHD;
  const unsigned short* Kb = qkvb + ((size_t)(1 * BATCH + b) * HB + h) * NSEQ * DHD;
  const unsigned short* Vb = Vt + (size_t)(b * HB + h) * DHD * NSEQ;

  const short8 zs = {0, 0, 0, 0, 0, 0, 0, 0};
  const f32x4 zero = {0.f, 0.f, 0.f, 0.f};

  // staging source pointers; wave issue i = w + 4*j (9 x 1KB per array).
  // K tile is a straight linear copy: LDS short off = c*8 == global short off.
  // V: LDS[dh][cg] <- V[dh][cg ^ (dh&7)]  (inverse swizzle on the source).
  const int vswz = ((lane & 7) ^ (lane >> 3)) * 8;
  const unsigned short* pKn[3];  // next K tile to ISSUE (rolls by 64*72)
  const unsigned short* pVn[3];  // next V tile to ISSUE (rolls by 64)
#pragma unroll
  for (int j = 0; j < 3; j++) {
    int i = w + 4 * j;
    int ii = (i < 9) ? i : 0;
    pKn[j] = Kb + ii * 512 + lane * 8;
    pVn[j] = Vb + (size_t)(ii * 8 + (lane >> 3)) * NSEQ + vswz;
  }

  // prologue: issue K(0) -> sK and V(0) -> sVt
#pragma unroll
  for (int j = 0; j < 3; j++) {
    int i = w + 4 * j;
    if (i < 9) {
      gload_lds16(pKn[j], sK + i * 512);
      gload_lds16(pVn[j], sVt + i * 512);
      pKn[j] += 64 * 72;
      pVn[j] += 64;
    }
  }

  // ones row (d=72) and zero rows (73..79) of V; staging never touches them
  for (int e = tid; e < 512; e += 256)
    sVt[72 * 64 + e] = (e < 64) ? (unsigned short)0x3F80 : (unsigned short)0;

  // Q fragments: 2 q-tiles per wave, rows q0 + w*32 + qt*16 + l16
  short8 aq[2][3];
#pragma unroll
  for (int qt = 0; qt < 2; qt++) {
    const unsigned short* qrow = Qb + (size_t)(q0 + w * 32 + qt * 16 + l16) * DHD;
    aq[qt][0] = *(const short8*)(qrow + quad * 8);
    aq[qt][1] = *(const short8*)(qrow + 32 + quad * 8);
    aq[qt][2] = (quad == 0) ? *(const short8*)(qrow + 64) : zs;
  }

  f32x4 o[2][5];
#pragma unroll
  for (int qt = 0; qt < 2; qt++)
#pragma unroll
    for (int nb = 0; nb < 5; nb++) o[qt][nb] = zero;

  // S-phase + pack (both q-tiles; each K fragment read once). SWAPPED
  // operands: D = S^T (row=kv, col=q); lane packs 4 consecutive kv with
  // 2 cvt_pk -> one b64 write into swizzled sP.
  auto sphase_pack = [&]() {
    f32x4 st[2][4];
    __builtin_amdgcn_s_setprio(1);
#pragma unroll
    for (int nk = 0; nk < 4; nk++) {
      const unsigned short* kr = sK + (nk * 16 + l16) * 72;
      short8 kf0 = *(const short8*)(kr + quad * 8);
      short8 kf1 = *(const short8*)(kr + 32 + quad * 8);
      short8 kf2 = *(const short8*)(kr + 64);  // uniform; bogus k-slots masked by aq[2]=0
      f32x4 s0 = zero, s1 = zero;
      s0 = __builtin_amdgcn_mfma_f32_16x16x32_bf16(kf0, aq[0][0], s0, 0, 0, 0);
      s1 = __builtin_amdgcn_mfma_f32_16x16x32_bf16(kf0, aq[1][0], s1, 0, 0, 0);
      s0 = __builtin_amdgcn_mfma_f32_16x16x32_bf16(kf1, aq[0][1], s0, 0, 0, 0);
      s1 = __builtin_amdgcn_mfma_f32_16x16x32_bf16(kf1, aq[1][1], s1, 0, 0, 0);
      s0 = __builtin_amdgcn_mfma_f32_16x16x32_bf16(kf2, aq[0][2], s0, 0, 0, 0);
      s1 = __builtin_amdgcn_mfma_f32_16x16x32_bf16(kf2, aq[1][2], s1, 0, 0, 0);
      st[0][nk] = s0;
      st[1][nk] = s1;
    }
    __builtin_amdgcn_s_setprio(0);
    // P = exp2(S^T): row = qt*64 + w*16 + l16, colshort = nk*16 + quad*4 + r.
    // Swizzled addr: row*64 + ((colshort>>3)^(row&7))*8 + (colshort&7).
#pragma unroll
    for (int qt = 0; qt < 2; qt++) {
      unsigned short* prow = sP + (qt * 64 + w * 16 + l16) * 64 + (quad & 1) * 4;
#pragma unroll
      for (int nk = 0; nk < 4; nk++) {
        int uoff = ((nk * 2 + (quad >> 1)) ^ s7) << 3;
        u32x2 pr;
        pr[0] = pkbf(exp2f(st[qt][nk][0]), exp2f(st[qt][nk][1]));
        pr[1] = pkbf(exp2f(st[qt][nk][2]), exp2f(st[qt][nk][3]));
        *(u32x2*)(prow + uoff) = pr;
      }
    }
  };

  // PV for the current tile: each V fragment read once, feeds both q-tiles.
  auto pv_phase = [&]() {
    __builtin_amdgcn_s_setprio(1);
#pragma unroll
    for (int kb = 0; kb < 2; kb++) {
      const unsigned short* pp =
          sP + (w * 16 + l16) * 64 + (((kb * 4 + quad) ^ s7) << 3);
      short8 pf0 = *(const short8*)pp;
      short8 pf1 = *(const short8*)(pp + 64 * 64);  // qt=1 rows (+64: same row&7)
#pragma unroll
      for (int nb = 0; nb < 5; nb++) {
        short8 vf = *(const short8*)(sVt + (nb * 16 + l16) * 64 +
                                     (((kb * 4 + quad) ^ s7) << 3));
        o[0][nb] = __builtin_amdgcn_mfma_f32_16x16x32_bf16(pf0, vf, o[0][nb], 0, 0, 0);
        o[1][nb] = __builtin_amdgcn_mfma_f32_16x16x32_bf16(pf1, vf, o[1][nb], 0, 0, 0);
      }
    }
    __builtin_amdgcn_s_setprio(0);
  };

  __syncthreads();   // drain K(0), V(0)

  for (int t = 0; t < 32; t++) {
    sphase_pack();           // S(t)+pack(t): reads sK, writes own sP rows

    __syncthreads();         // F: sK readers done; V(t) DMA drained (prev E)

    if (t < 31) {            // issue K(t+1) into sK (readers finished)
#pragma unroll
      for (int j = 0; j < 3; j++) {
        int i = w + 4 * j;
        if (i < 9) { gload_lds16(pKn[j], sK + i * 512); pKn[j] += 64 * 72; }
      }
    }

    pv_phase();              // PV(t): reads sVt=V(t), sP=P(t)

    __syncthreads();         // E: sVt readers done; K(t+1) DMA drained

    if (t < 31) {            // issue V(t+1); drains at next F
#pragma unroll
      for (int j = 0; j < 3; j++) {
        int i = w + 4 * j;
        if (i < 9) { gload_lds16(pVn[j], sVt + i * 512); pVn[j] += 64; }
      }
    }
  }

  // epilogue: l sits at dh=72 (nb=4, l16=8); broadcast within quad, normalize
#pragma unroll
  for (int qt = 0; qt < 2; qt++) {
    float inv[4];
#pragma unroll
    for (int r = 0; r < 4; r++)
      inv[r] = 1.0f / __shfl(o[qt][4][r], (quad << 4) + 8, 64);
    const int qrow = q0 + w * 32 + qt * 16 + quad * 4;
#pragma unroll
    for (int nb = 0; nb < 5; nb++) {
      int dh = nb * 16 + l16;
      if (dh < DHD) {
#pragma unroll
        for (int r = 0; r < 4; r++)
          AO[((size_t)b * NSEQ + qrow + r) * CDIM + h * DHD + dh] =
              f2bf(o[qt][nb][r] * inv[r]);
      }
    }
  }
}

// ---------------------------------------------------------------------------
extern "C" void kernel_launch(void* const* d_in, const int* in_sizes, int n_in,
                              void* d_out, int out_size, void* d_ws, size_t ws_size,
                              hipStream_t stream) {
  const float* x      = (const float*)d_in[0];
  const float* w_qkv  = (const float*)d_in[1];
  const float* w_proj = (const float*)d_in[2];
  const float* b_proj = (const float*)d_in[3];
  const float* qnw    = (const float*)d_in[4];
  const float* knw    = (const float*)d_in[5];
  float* out = (float*)d_out;

  char* ws = (char*)d_ws;
  // layout (bytes): xb 18.9M | wqkvb 8.0M | wprojb 2.7M | qkvb 37.7M | Vt 18.9M
  // AO aliases xb (xb dead after gemm1). Total 86.1 MB.
  unsigned short* xb    = (unsigned short*)(ws);
  unsigned short* wqkvb = (unsigned short*)(ws + 18874368);
  unsigned short* wprojb= (unsigned short*)(ws + 26836992);
  unsigned short* qkvb  = (unsigned short*)(ws + 29491200);
  unsigned short* Vt    = (unsigned short*)(ws + 67239936);
  unsigned short* AO    = xb;

  cvt_bf16<<<dim3((CVT_CHUNKS + 255) / 256), 256, 0, stream>>>(
      x, w_qkv, w_proj, xb, wqkvb, wprojb);
  gemm_bt<1><<<dim3(D3 / 128, NT / 128), 256, 0, stream>>>(
      xb, wqkvb, nullptr, qkvb, Vt, NT, D3, CDIM);
  rope_rms<<<dim3(NT), 256, 0, stream>>>(qkvb, qnw, knw);
  flash_attn<<<dim3(NSEQ / 128, HB, BATCH), 256, 0, stream>>>(qkvb, Vt, AO);
  gemm_bt<0><<<dim3(CDIM / 128, NT / 128), 256, 0, stream>>>(
      AO, wprojb, b_proj, out, nullptr, NT, CDIM, CDIM);
}

// Round 8
// 354.287 us; speedup vs baseline: 1.3324x; 1.0377x over previous
//
#include <hip/hip_runtime.h>
#include <stdint.h>

// Problem constants
#define BATCH 4
#define NSEQ  2048
#define CDIM  1152
#define HB    16
#define DHD   72
#define D3    3456
#define NT    8192    // BATCH*NSEQ

typedef __attribute__((ext_vector_type(8))) short short8;       // 8 bf16 (4 VGPRs)
typedef __attribute__((ext_vector_type(8))) unsigned short u16x8;
typedef __attribute__((ext_vector_type(4))) unsigned short u16x4;
typedef __attribute__((ext_vector_type(2))) unsigned int u32x2;
typedef __attribute__((ext_vector_type(4))) float f32x4;

__device__ __forceinline__ float bf2f(unsigned short u) {
  return __uint_as_float(((unsigned)u) << 16);
}
__device__ __forceinline__ unsigned short f2bf(float f) {
  unsigned u = __float_as_uint(f);
  u += 0x7FFF + ((u >> 16) & 1);   // RNE
  return (unsigned short)(u >> 16);
}
// packed 2xf32 -> 2xbf16 (RNE) in one instruction (T12 recipe; no builtin)
__device__ __forceinline__ unsigned pkbf(float lo, float hi) {
  unsigned r;
  asm("v_cvt_pk_bf16_f32 %0, %1, %2" : "=v"(r) : "v"(lo), "v"(hi));
  return r;
}

// async 16B global->LDS copy: per-lane global addr, LDS dest = wave-uniform base + lane*16
__device__ __forceinline__ void gload_lds16(const unsigned short* g, unsigned short* l) {
  __builtin_amdgcn_global_load_lds(
      (const __attribute__((address_space(1))) void*)g,
      (__attribute__((address_space(3))) void*)l, 16, 0, 0);
}

// ---------------------------------------------------------------------------
// fp32 -> bf16 conversion prepass for x, w_qkv, w_proj (memory-bound).
// ---------------------------------------------------------------------------
#define XN    ((size_t)NT * CDIM)        // 9,437,184
#define WQN   ((size_t)D3 * CDIM)        // 3,981,312
#define WPN   ((size_t)CDIM * CDIM)      // 1,327,104
#define CVT_CHUNKS ((XN + WQN + WPN) / 4)  // 3,686,400 float4 chunks

__global__ __launch_bounds__(256) void cvt_bf16(
    const float* __restrict__ x, const float* __restrict__ wq,
    const float* __restrict__ wp, unsigned short* __restrict__ xb,
    unsigned short* __restrict__ wqb, unsigned short* __restrict__ wpb) {
  size_t c = (size_t)blockIdx.x * 256 + threadIdx.x;
  if (c >= CVT_CHUNKS) return;
  const float* src;
  unsigned short* dst;
  size_t e = c * 4;
  if (e < XN) { src = x + e; dst = xb + e; }
  else if (e < XN + WQN) { src = wq + (e - XN); dst = wqb + (e - XN); }
  else { src = wp + (e - XN - WQN); dst = wpb + (e - XN - WQN); }
  f32x4 v = *(const f32x4*)src;
  u16x4 r;
#pragma unroll
  for (int i = 0; i < 4; i++) r[i] = f2bf(v[i]);
  *(u16x4*)dst = r;
}

// ---------------------------------------------------------------------------
// GEMM-256: qkv = x * Wqkv^T, bf16 in, fp32 acc, bf16 scatter out.
// BM=BN=256, BK=64, 512 thr = 8 waves (2M x 4N; per-wave 128x64 output).
// Double-buffered LDS (128 KB, 1 block/CU, 2 waves/SIMD). Per K-tile:
//   phase kk=0: 12 ds_read_b128 (swz) | issue 4 A-prefetch(t+1) | 32 MFMA
//   phase kk=1: 12 ds_read_b128 (swz) | issue 4 B-prefetch(t+1) | 32 MFMA
//   __syncthreads (vmcnt(0) drains the 8 loads issued 1-2 phases earlier)
// T21 both-sides XOR swizzle: LDS[r][u] = G[r][u ^ (r&7)] via pre-swizzled
// source; reads use LDS[R][U ^ (R&7)] -> conflict-free b128.
// Grid (14, 32): N padded to 3584 -- the last N-tile reads B rows
// 3456..3583 from adjacent workspace (garbage stays in its own output
// columns, which the guarded epilogue skips). XCD banding: xcd owns 4
// contiguous M-tiles (A-band 2.4 MB L2-resident), rows-fastest.
// ---------------------------------------------------------------------------
__global__ __launch_bounds__(512, 2) void gemm256_qkv(
    const unsigned short* __restrict__ A, const unsigned short* __restrict__ Bt,
    unsigned short* __restrict__ qkvb, unsigned short* __restrict__ Vt) {
  __shared__ __attribute__((aligned(16))) unsigned short sA[2 * 256 * 64];  // 64 KB
  __shared__ __attribute__((aligned(16))) unsigned short sB[2 * 256 * 64];  // 64 KB

  const int K = CDIM;
  const int tid  = threadIdx.x;
  const int lane = tid & 63;
  const int w    = tid >> 6;          // 0..7
  const int wm   = w >> 2, wn = w & 3;
  const int quad = lane >> 4, l16 = lane & 15;
  const int s7l  = l16 & 7;

  // XCD banding: lb in [0,448); xcd owns m-tiles [xcd*4, xcd*4+4), rows fastest.
  const int lb  = blockIdx.y * gridDim.x + blockIdx.x;   // gridDim.x = 14
  const int xcd = lb & 7;
  const int pos = lb >> 3;            // 0..55
  const int m0 = (xcd * 4 + (pos & 3)) * 256;
  const int n0 = (pos >> 2) * 256;    // 0..13 tiles (tile 13 partial)

  // staging: 4 groups of 64 rows x 64 cols per array; wave w stages rows
  // g*64 + w*8 + (lane>>3), source col unit pre-swizzled by row&7.
  const int r8 = lane >> 3;
  const int cu = (lane & 7) ^ r8;
  const unsigned short* gA = A  + (size_t)(m0 + w * 8 + r8) * K + cu * 8;
  const unsigned short* gB = Bt + (size_t)(n0 + w * 8 + r8) * K + cu * 8;

  const f32x4 zero = {0.f, 0.f, 0.f, 0.f};
  f32x4 acc[8][4];
#pragma unroll
  for (int i = 0; i < 8; i++)
#pragma unroll
    for (int j = 0; j < 4; j++) acc[i][j] = zero;

  // prologue: stage tile 0 -> buf 0
#pragma unroll
  for (int g = 0; g < 4; g++) {
    gload_lds16(gA + (size_t)g * 64 * K, sA + g * 4096 + w * 512);
    gload_lds16(gB + (size_t)g * 64 * K, sB + g * 4096 + w * 512);
  }
  __syncthreads();

  for (int t = 0; t < 18; t++) {
    const unsigned short* A_ = sA + (t & 1) * 16384;
    const unsigned short* B_ = sB + (t & 1) * 16384;
    unsigned short* An = sA + ((t + 1) & 1) * 16384;
    unsigned short* Bn = sB + ((t + 1) & 1) * 16384;
    const int ktn = (t + 1) * 64;

#pragma unroll
    for (int kk = 0; kk < 2; kk++) {
      short8 a[8], b[4];
#pragma unroll
      for (int i = 0; i < 8; i++)
        a[i] = *(const short8*)(A_ + (wm * 128 + i * 16 + l16) * 64 +
                                (((kk * 4 + quad) ^ s7l) << 3));
#pragma unroll
      for (int j = 0; j < 4; j++)
        b[j] = *(const short8*)(B_ + (wn * 64 + j * 16 + l16) * 64 +
                                (((kk * 4 + quad) ^ s7l) << 3));

      if (t < 17) {  // front-loaded prefetch: A halves in kk=0, B in kk=1
#pragma unroll
        for (int g = 0; g < 4; g++) {
          if (kk == 0)
            gload_lds16(gA + (size_t)g * 64 * K + ktn, An + g * 4096 + w * 512);
          else
            gload_lds16(gB + (size_t)g * 64 * K + ktn, Bn + g * 4096 + w * 512);
        }
      }

      __builtin_amdgcn_s_setprio(1);
#pragma unroll
      for (int i = 0; i < 8; i++)
#pragma unroll
        for (int j = 0; j < 4; j++)
          acc[i][j] = __builtin_amdgcn_mfma_f32_16x16x32_bf16(a[i], b[j], acc[i][j], 0, 0, 0);
      __builtin_amdgcn_s_setprio(0);
    }
    __syncthreads();   // drains prefetch (issued 1-2 phases ago); buffer handoff
  }

  // epilogue: D row = quad*4+r, col = l16; scatter Q,K -> qkvb, V -> Vt.
#pragma unroll
  for (int i = 0; i < 8; i++) {
    int row = m0 + wm * 128 + i * 16 + quad * 4;
    int b_ = row >> 11;               // rows of 4 never straddle the 2048 bdry
    int n  = row & 2047;
#pragma unroll
    for (int j = 0; j < 4; j++) {
      int col = n0 + wn * 64 + j * 16 + l16;
      if (col < D3) {
        int s  = col / CDIM;
        int rm = col - s * CDIM;
        int h  = rm / DHD;
        int dh = rm - h * DHD;
        if (s == 2) {
#pragma unroll
          for (int r = 0; r < 4; r++)
            Vt[((size_t)(b_ * HB + h) * DHD + dh) * NSEQ + n + r] = f2bf(acc[i][j][r]);
        } else {
#pragma unroll
          for (int r = 0; r < 4; r++)
            qkvb[(((size_t)(s * BATCH + b_) * HB + h) * NSEQ + (n + r)) * DHD + dh] =
                f2bf(acc[i][j][r]);
        }
      }
    }
  }
}

// ---------------------------------------------------------------------------
// GEMM-BT (bf16 in): C[M,Dn] = A[M,K]*Bt[Dn,K]^T (+bias), fp32 acc.
// BM=BN=128, BK=64, 256 thr = 4 waves, 16x16x32 MFMA, T21 both-sides swizzle,
// XCD band mapping. Used for the output projection (gemm2).
// ---------------------------------------------------------------------------
__global__ __launch_bounds__(256) void gemm_bt(
    const unsigned short* __restrict__ A, const unsigned short* __restrict__ Bt,
    const float* __restrict__ bias, float* __restrict__ Cout, int M, int Dn, int K) {
  __shared__ __attribute__((aligned(16))) unsigned short sA[128 * 64];  // 16 KB
  __shared__ __attribute__((aligned(16))) unsigned short sB[128 * 64];  // 16 KB

  const int tid  = threadIdx.x;
  const int lane = tid & 63;
  const int w    = tid >> 6;
  const int wm   = w >> 1, wn = w & 1;
  const int quad = lane >> 4, l16 = lane & 15;
  const int s7l  = l16 & 7;

  const int gx  = gridDim.x;
  const int lb  = blockIdx.y * gx + blockIdx.x;
  const int xcd = lb & 7;
  const int pos = lb >> 3;
  const int m0 = ((xcd << 3) + (pos & 7)) * 128;
  const int n0 = (pos >> 3) * 128;

  const int r8 = lane >> 3;
  const int cu = (lane & 7) ^ r8;
  const unsigned short* gA = A  + (size_t)(m0 + w * 32 + r8) * K + cu * 8;
  const unsigned short* gB = Bt + (size_t)(n0 + w * 32 + r8) * K + cu * 8;

  const f32x4 zero = {0.f, 0.f, 0.f, 0.f};
  f32x4 acc[4][4];
#pragma unroll
  for (int i = 0; i < 4; i++)
#pragma unroll
    for (int j = 0; j < 4; j++) acc[i][j] = zero;

  for (int kt = 0; kt < K; kt += 64) {
#pragma unroll
    for (int i = 0; i < 4; i++) {
      gload_lds16(gA + (size_t)i * 8 * K + kt, sA + (w * 4 + i) * 512);
      gload_lds16(gB + (size_t)i * 8 * K + kt, sB + (w * 4 + i) * 512);
    }
    __syncthreads();

#pragma unroll
    for (int kk = 0; kk < 2; kk++) {
      short8 a[4], b[4];
#pragma unroll
      for (int i = 0; i < 4; i++) {
        a[i] = *(const short8*)(sA + (wm * 64 + i * 16 + l16) * 64 +
                                (((kk * 4 + quad) ^ s7l) << 3));
        b[i] = *(const short8*)(sB + (wn * 64 + i * 16 + l16) * 64 +
                                (((kk * 4 + quad) ^ s7l) << 3));
      }
#pragma unroll
      for (int i = 0; i < 4; i++)
#pragma unroll
        for (int j = 0; j < 4; j++)
          acc[i][j] = __builtin_amdgcn_mfma_f32_16x16x32_bf16(a[i], b[j], acc[i][j], 0, 0, 0);
    }
    __syncthreads();
  }

#pragma unroll
  for (int i = 0; i < 4; i++) {
    int row = m0 + wm * 64 + i * 16 + quad * 4;
#pragma unroll
    for (int j = 0; j < 4; j++) {
      int col = n0 + wn * 64 + j * 16 + l16;
      float bb = bias ? bias[col] : 0.f;
#pragma unroll
      for (int r = 0; r < 4; r++)
        Cout[(size_t)(row + r) * Dn + col] = acc[i][j][r] + bb;
    }
  }
}

// ---------------------------------------------------------------------------
// RoPE (halves convention) + RMSNorm on q,k IN-PLACE on qkvb[s][b][h][n][72].
// One block per (b,n). Vectorized global I/O (u16x8) through LDS; RoPE
// pair-wise in LDS; per-head RMS reduce 4 lanes/head x 2 waves + shfl.
// Q pre-scaled by 72^-0.5*log2(e) so flash_attn's softmax is exp2(S).
// ---------------------------------------------------------------------------
__global__ __launch_bounds__(256) void rope_rms(
    unsigned short* __restrict__ qkvb,
    const float* __restrict__ qw, const float* __restrict__ kw) {
  const int blk = blockIdx.x;
  const int b = blk >> 11;
  const int n = blk & 2047;
  const int tid = threadIdx.x;

  __shared__ float sv[2][CDIM];   // 9216 B
  __shared__ float srsq[2][HB];

  const float nf = (float)n;
  const float l2t_over_half = 13.287712379549449f / 36.0f;  // log2(10000)/36
  const float scale2 = 0.17002329230297715f;                // 72^-0.5 * log2(e)

  for (int g = tid; g < 288; g += 256) {
    int sel = (g >= 144) ? 1 : 0;
    int gg  = g - sel * 144;
    int h   = gg / 9;
    int u   = gg - h * 9;
    const unsigned short* src =
        qkvb + (((size_t)(sel * BATCH + b) * HB + h) * NSEQ + n) * DHD + u * 8;
    u16x8 v = *(const u16x8*)src;
    float* dst = &sv[sel][h * DHD + u * 8];
#pragma unroll
    for (int r = 0; r < 8; r++) dst[r] = bf2f(v[r]);
  }
  __syncthreads();

  for (int p = tid; p < 1152; p += 256) {
    int sel = (p >= 576) ? 1 : 0;
    int pp  = p - sel * 576;
    int h   = pp / 36;
    int i   = pp - h * 36;
    float* row = &sv[sel][h * DHD];
    float x1 = row[i], x2 = row[i + 36];
    float ang = nf * exp2f(-l2t_over_half * (float)i);
    float sn, cs;
    __sincosf(ang, &sn, &cs);
    row[i]      = x1 * cs - x2 * sn;
    row[i + 36] = x2 * cs + x1 * sn;
  }
  __syncthreads();

  if (tid < 128) {
    int sel = tid >> 6;
    int h = (tid & 63) >> 2, p = tid & 3;
    float s = 0.f;
#pragma unroll
    for (int d = 0; d < 18; d++) {
      float v = sv[sel][h * DHD + p * 18 + d];
      s += v * v;
    }
    s += __shfl_xor(s, 1);
    s += __shfl_xor(s, 2);
    if (p == 0)
      srsq[sel][h] = rsqrtf(s * (1.0f / 72.0f) + 1e-6f) * (sel ? 1.0f : scale2);
  }
  __syncthreads();

  for (int g = tid; g < 288; g += 256) {
    int sel = (g >= 144) ? 1 : 0;
    int gg  = g - sel * 144;
    int h   = gg / 9;
    int u   = gg - h * 9;
    float rs = srsq[sel][h];
    const float* wn = (sel ? kw : qw) + u * 8;
    const float* s = &sv[sel][h * DHD + u * 8];
    u16x8 o;
#pragma unroll
    for (int r = 0; r < 8; r++) o[r] = f2bf(s[r] * rs * wn[r]);
    unsigned short* dst =
        qkvb + (((size_t)(sel * BATCH + b) * HB + h) * NSEQ + n) * DHD + u * 8;
    *(u16x8*)dst = o;
  }
}

// ---------------------------------------------------------------------------
// Flash attention, no-max softmax (Q pre-scaled; exp2 never overflows since
// q,k are RMS-normed). Block = 128 q-rows x head x batch; 4 waves x
// (2 fused q-tiles of 16). KV tiles of 64. S^T via swapped mfma(K,Q);
// cvt_pk pack -> b64 writes into XOR-swizzled sP. 35840 B LDS -> 4 blk/CU.
// [UNCHANGED from R5/R7 -- control]
// ---------------------------------------------------------------------------
__global__ __launch_bounds__(256, 4) void flash_attn(
    const unsigned short* __restrict__ qkvb, const unsigned short* __restrict__ Vt,
    unsigned short* __restrict__ AO) {
  __shared__ __attribute__((aligned(16))) unsigned short sK[64 * 72];    //  9216 B
  __shared__ __attribute__((aligned(16))) unsigned short sVt[80 * 64];   // 10240 B
  __shared__ __attribute__((aligned(16))) unsigned short sP[128 * 64];   // 16384 B

  const int tid  = threadIdx.x;
  const int w    = tid >> 6;
  const int lane = tid & 63;
  const int quad = lane >> 4, l16 = lane & 15;
  const int s7   = l16 & 7;
  const int q0 = blockIdx.x * 128;
  const int h = blockIdx.y, b = blockIdx.z;

  const unsigned short* Qb = qkvb + ((size_t)(0 * BATCH + b) * HB + h) * NSEQ * DHD;
  const unsigned short* Kb = qkvb + ((size_t)(1 * BATCH + b) * HB + h) * NSEQ * DHD;
  const unsigned short* Vb = Vt + (size_t)(b * HB + h) * DHD * NSEQ;

  const short8 zs = {0, 0, 0, 0, 0, 0, 0, 0};
  const f32x4 zero = {0.f, 0.f, 0.f, 0.f};

  const int vswz = ((lane & 7) ^ (lane >> 3)) * 8;
  const unsigned short* pKn[3];
  const unsigned short* pVn[3];
#pragma unroll
  for (int j = 0; j < 3; j++) {
    int i = w + 4 * j;
    int ii = (i < 9) ? i : 0;
    pKn[j] = Kb + ii * 512 + lane * 8;
    pVn[j] = Vb + (size_t)(ii * 8 + (lane >> 3)) * NSEQ + vswz;
  }

#pragma unroll
  for (int j = 0; j < 3; j++) {
    int i = w + 4 * j;
    if (i < 9) {
      gload_lds16(pKn[j], sK + i * 512);
      gload_lds16(pVn[j], sVt + i * 512);
      pKn[j] += 64 * 72;
      pVn[j] += 64;
    }
  }

  for (int e = tid; e < 512; e += 256)
    sVt[72 * 64 + e] = (e < 64) ? (unsigned short)0x3F80 : (unsigned short)0;

  short8 aq[2][3];
#pragma unroll
  for (int qt = 0; qt < 2; qt++) {
    const unsigned short* qrow = Qb + (size_t)(q0 + w * 32 + qt * 16 + l16) * DHD;
    aq[qt][0] = *(const short8*)(qrow + quad * 8);
    aq[qt][1] = *(const short8*)(qrow + 32 + quad * 8);
    aq[qt][2] = (quad == 0) ? *(const short8*)(qrow + 64) : zs;
  }

  f32x4 o[2][5];
#pragma unroll
  for (int qt = 0; qt < 2; qt++)
#pragma unroll
    for (int nb = 0; nb < 5; nb++) o[qt][nb] = zero;

  auto sphase_pack = [&]() {
    f32x4 st[2][4];
    __builtin_amdgcn_s_setprio(1);
#pragma unroll
    for (int nk = 0; nk < 4; nk++) {
      const unsigned short* kr = sK + (nk * 16 + l16) * 72;
      short8 kf0 = *(const short8*)(kr + quad * 8);
      short8 kf1 = *(const short8*)(kr + 32 + quad * 8);
      short8 kf2 = *(const short8*)(kr + 64);
      f32x4 s0 = zero, s1 = zero;
      s0 = __builtin_amdgcn_mfma_f32_16x16x32_bf16(kf0, aq[0][0], s0, 0, 0, 0);
      s1 = __builtin_amdgcn_mfma_f32_16x16x32_bf16(kf0, aq[1][0], s1, 0, 0, 0);
      s0 = __builtin_amdgcn_mfma_f32_16x16x32_bf16(kf1, aq[0][1], s0, 0, 0, 0);
      s1 = __builtin_amdgcn_mfma_f32_16x16x32_bf16(kf1, aq[1][1], s1, 0, 0, 0);
      s0 = __builtin_amdgcn_mfma_f32_16x16x32_bf16(kf2, aq[0][2], s0, 0, 0, 0);
      s1 = __builtin_amdgcn_mfma_f32_16x16x32_bf16(kf2, aq[1][2], s1, 0, 0, 0);
      st[0][nk] = s0;
      st[1][nk] = s1;
    }
    __builtin_amdgcn_s_setprio(0);
#pragma unroll
    for (int qt = 0; qt < 2; qt++) {
      unsigned short* prow = sP + (qt * 64 + w * 16 + l16) * 64 + (quad & 1) * 4;
#pragma unroll
      for (int nk = 0; nk < 4; nk++) {
        int uoff = ((nk * 2 + (quad >> 1)) ^ s7) << 3;
        u32x2 pr;
        pr[0] = pkbf(exp2f(st[qt][nk][0]), exp2f(st[qt][nk][1]));
        pr[1] = pkbf(exp2f(st[qt][nk][2]), exp2f(st[qt][nk][3]));
        *(u32x2*)(prow + uoff) = pr;
      }
    }
  };

  auto pv_phase = [&]() {
    __builtin_amdgcn_s_setprio(1);
#pragma unroll
    for (int kb = 0; kb < 2; kb++) {
      const unsigned short* pp =
          sP + (w * 16 + l16) * 64 + (((kb * 4 + quad) ^ s7) << 3);
      short8 pf0 = *(const short8*)pp;
      short8 pf1 = *(const short8*)(pp + 64 * 64);
#pragma unroll
      for (int nb = 0; nb < 5; nb++) {
        short8 vf = *(const short8*)(sVt + (nb * 16 + l16) * 64 +
                                     (((kb * 4 + quad) ^ s7) << 3));
        o[0][nb] = __builtin_amdgcn_mfma_f32_16x16x32_bf16(pf0, vf, o[0][nb], 0, 0, 0);
        o[1][nb] = __builtin_amdgcn_mfma_f32_16x16x32_bf16(pf1, vf, o[1][nb], 0, 0, 0);
      }
    }
    __builtin_amdgcn_s_setprio(0);
  };

  __syncthreads();

  for (int t = 0; t < 32; t++) {
    sphase_pack();

    __syncthreads();

    if (t < 31) {
#pragma unroll
      for (int j = 0; j < 3; j++) {
        int i = w + 4 * j;
        if (i < 9) { gload_lds16(pKn[j], sK + i * 512); pKn[j] += 64 * 72; }
      }
    }

    pv_phase();

    __syncthreads();

    if (t < 31) {
#pragma unroll
      for (int j = 0; j < 3; j++) {
        int i = w + 4 * j;
        if (i < 9) { gload_lds16(pVn[j], sVt + i * 512); pVn[j] += 64; }
      }
    }
  }

#pragma unroll
  for (int qt = 0; qt < 2; qt++) {
    float inv[4];
#pragma unroll
    for (int r = 0; r < 4; r++)
      inv[r] = 1.0f / __shfl(o[qt][4][r], (quad << 4) + 8, 64);
    const int qrow = q0 + w * 32 + qt * 16 + quad * 4;
#pragma unroll
    for (int nb = 0; nb < 5; nb++) {
      int dh = nb * 16 + l16;
      if (dh < DHD) {
#pragma unroll
        for (int r = 0; r < 4; r++)
          AO[((size_t)b * NSEQ + qrow + r) * CDIM + h * DHD + dh] =
              f2bf(o[qt][nb][r] * inv[r]);
      }
    }
  }
}

// ---------------------------------------------------------------------------
extern "C" void kernel_launch(void* const* d_in, const int* in_sizes, int n_in,
                              void* d_out, int out_size, void* d_ws, size_t ws_size,
                              hipStream_t stream) {
  const float* x      = (const float*)d_in[0];
  const float* w_qkv  = (const float*)d_in[1];
  const float* w_proj = (const float*)d_in[2];
  const float* b_proj = (const float*)d_in[3];
  const float* qnw    = (const float*)d_in[4];
  const float* knw    = (const float*)d_in[5];
  float* out = (float*)d_out;

  char* ws = (char*)d_ws;
  // layout (bytes): xb 18.9M | wqkvb 8.0M | wprojb 2.7M | qkvb 37.7M | Vt 18.9M
  // AO aliases xb (xb dead after gemm1). Total 86.1 MB.
  unsigned short* xb    = (unsigned short*)(ws);
  unsigned short* wqkvb = (unsigned short*)(ws + 18874368);
  unsigned short* wprojb= (unsigned short*)(ws + 26836992);
  unsigned short* qkvb  = (unsigned short*)(ws + 29491200);
  unsigned short* Vt    = (unsigned short*)(ws + 67239936);
  unsigned short* AO    = xb;

  cvt_bf16<<<dim3((CVT_CHUNKS + 255) / 256), 256, 0, stream>>>(
      x, w_qkv, w_proj, xb, wqkvb, wprojb);
  gemm256_qkv<<<dim3(14, 32), 512, 0, stream>>>(xb, wqkvb, qkvb, Vt);
  rope_rms<<<dim3(NT), 256, 0, stream>>>(qkvb, qnw, knw);
  flash_attn<<<dim3(NSEQ / 128, HB, BATCH), 256, 0, stream>>>(qkvb, Vt, AO);
  gemm_bt<<<dim3(CDIM / 128, NT / 128), 256, 0, stream>>>(
      AO, wprojb, b_proj, out, NT, CDIM, CDIM);
}